// Round 10
// baseline (1052.885 us; speedup 1.0000x reference)
//
#include <hip/hip_runtime.h>
#include <cmath>

#define BB 128
#define TT 256
#define DD 512
#define HH 256
#define G3 768   // 3*H

typedef float f32x4 __attribute__((ext_vector_type(4)));
typedef short s16x8 __attribute__((ext_vector_type(8)));
typedef unsigned long long ull;
typedef unsigned short u16;

// v_dot2_f32_f16: acc += w.f16[0]*h.f16[0] + w.f16[1]*h.f16[1]  (CDNA1+)
#define DOT2(acc, w, h) \
  asm("v_dot2_f32_f16 %0, %1, %2, %0" : "+v"(acc) : "v"(w), "v"(h))

// RNE float -> (hi bf16, lo bf16) split: x ~= hi + lo, |err| ~ 2^-17 |x|
__device__ __forceinline__ void split_bf16(float x, u16& h, u16& l)
{
  unsigned u = __float_as_uint(x);
  unsigned hr = u + 0x7fffu + ((u >> 16) & 1u);
  h = (u16)(hr >> 16);
  float hf = __uint_as_float((unsigned)h << 16);
  float lo = x - hf;
  unsigned u2 = __float_as_uint(lo);
  unsigned lr2 = u2 + 0x7fffu + ((u2 >> 16) & 1u);
  l = (u16)(lr2 >> 16);
}

__device__ __forceinline__ float bf_hl(u16 h, u16 l)
{
  return __uint_as_float((unsigned)h << 16) + __uint_as_float((unsigned)l << 16);
}

// ---- f32 -> (hi,lo) bf16 plane conversion, 8 elems/thread ---------------
__global__ __launch_bounds__(256) void cvt_split_kernel(
    const float* __restrict__ src, u16* __restrict__ dh,
    u16* __restrict__ dl, int n8)
{
  const int i = blockIdx.x * 256 + threadIdx.x;
  if (i >= n8) return;
  const float4 v0 = *(const float4*)(src + (size_t)i * 8);
  const float4 v1 = *(const float4*)(src + (size_t)i * 8 + 4);
  float f[8] = {v0.x, v0.y, v0.z, v0.w, v1.x, v1.y, v1.z, v1.w};
  u16 hh[8], ll[8];
#pragma unroll
  for (int j = 0; j < 8; j++) split_bf16(f[j], hh[j], ll[j]);
  *(uint4*)(dh + (size_t)i * 8) = *(const uint4*)hh;
  *(uint4*)(dl + (size_t)i * 8) = *(const uint4*)ll;
}

// ---- pure-MFMA split-bf16 GEMM: C = bias + A*W^T, pre-split planes ------
// (unchanged from R6-R9 -- pass-verified). 3 MFMAs per fragment (hh+hl+lh).
__global__ __launch_bounds__(256) void gemm_bf3(
    const u16* __restrict__ Ah, const u16* __restrict__ Al,
    const u16* __restrict__ Wh, const u16* __restrict__ Wl,
    const float* __restrict__ bias, float* __restrict__ C,
    int M, int N, int K)
{
  __shared__ unsigned aH[128][20], aL[128][20], bH[128][20], bL[128][20];
  const int tid = threadIdx.x;
  const int row0 = blockIdx.y * 128, col0 = blockIdx.x * 128;
  const int wid = tid >> 6, lane = tid & 63;
  const int wm = wid >> 1, wn = wid & 1;
  const int lr = lane & 15, kq = lane >> 4;
  const int sr = tid >> 1, sh = tid & 1;     // staging: row sr, k-half sh

  f32x4 acc[4][4];
#pragma unroll
  for (int i = 0; i < 4; i++)
#pragma unroll
    for (int j = 0; j < 4; j++) acc[i][j] = (f32x4){0.f, 0.f, 0.f, 0.f};

  const u16* pah = Ah + (size_t)(row0 + sr) * K + sh * 16;
  const u16* pal = Al + (size_t)(row0 + sr) * K + sh * 16;
  const u16* pwh = Wh + (size_t)(col0 + sr) * K + sh * 16;
  const u16* pwl = Wl + (size_t)(col0 + sr) * K + sh * 16;
  const bool wok = (col0 + sr) < N;
  const uint4 z4 = make_uint4(0u, 0u, 0u, 0u);

  uint4 rah0 = *(const uint4*)(pah), rah1 = *(const uint4*)(pah + 8);
  uint4 ral0 = *(const uint4*)(pal), ral1 = *(const uint4*)(pal + 8);
  uint4 rbh0 = wok ? *(const uint4*)(pwh) : z4;
  uint4 rbh1 = wok ? *(const uint4*)(pwh + 8) : z4;
  uint4 rbl0 = wok ? *(const uint4*)(pwl) : z4;
  uint4 rbl1 = wok ? *(const uint4*)(pwl + 8) : z4;

  for (int k0 = 0; k0 < K; k0 += 32) {
    __syncthreads();               // previous compute done reading LDS
    ((uint4*)&aH[sr][sh * 8])[0] = rah0; ((uint4*)&aH[sr][sh * 8])[1] = rah1;
    ((uint4*)&aL[sr][sh * 8])[0] = ral0; ((uint4*)&aL[sr][sh * 8])[1] = ral1;
    ((uint4*)&bH[sr][sh * 8])[0] = rbh0; ((uint4*)&bH[sr][sh * 8])[1] = rbh1;
    ((uint4*)&bL[sr][sh * 8])[0] = rbl0; ((uint4*)&bL[sr][sh * 8])[1] = rbl1;
    __syncthreads();
    if (k0 + 32 < K) {             // register-prefetch next chunk
      rah0 = *(const uint4*)(pah + k0 + 32); rah1 = *(const uint4*)(pah + k0 + 40);
      ral0 = *(const uint4*)(pal + k0 + 32); ral1 = *(const uint4*)(pal + k0 + 40);
      rbh0 = wok ? *(const uint4*)(pwh + k0 + 32) : z4;
      rbh1 = wok ? *(const uint4*)(pwh + k0 + 40) : z4;
      rbl0 = wok ? *(const uint4*)(pwl + k0 + 32) : z4;
      rbl1 = wok ? *(const uint4*)(pwl + k0 + 40) : z4;
    }
    s16x8 ah[4], al4[4], bh4[4], bl4[4];
#pragma unroll
    for (int f = 0; f < 4; f++) {
      const int ra = wm * 64 + f * 16 + lr;
      const int rb = wn * 64 + f * 16 + lr;
      ah[f]  = *(const s16x8*)((const short*)&aH[ra][0] + kq * 8);
      al4[f] = *(const s16x8*)((const short*)&aL[ra][0] + kq * 8);
      bh4[f] = *(const s16x8*)((const short*)&bH[rb][0] + kq * 8);
      bl4[f] = *(const s16x8*)((const short*)&bL[rb][0] + kq * 8);
    }
#pragma unroll
    for (int mf = 0; mf < 4; mf++)
#pragma unroll
      for (int nf = 0; nf < 4; nf++) {
        acc[mf][nf] = __builtin_amdgcn_mfma_f32_16x16x32_bf16(ah[mf],  bh4[nf], acc[mf][nf], 0, 0, 0);
        acc[mf][nf] = __builtin_amdgcn_mfma_f32_16x16x32_bf16(ah[mf],  bl4[nf], acc[mf][nf], 0, 0, 0);
        acc[mf][nf] = __builtin_amdgcn_mfma_f32_16x16x32_bf16(al4[mf], bh4[nf], acc[mf][nf], 0, 0, 0);
      }
  }
  // epilogue: C/D layout col=lane&15, row=(lane>>4)*4+reg
#pragma unroll
  for (int mf = 0; mf < 4; mf++)
#pragma unroll
    for (int nf = 0; nf < 4; nf++) {
      const int c = col0 + wn * 64 + nf * 16 + lr;
      if (c < N) {
        const float bsv = bias[c];
#pragma unroll
        for (int i = 0; i < 4; i++) {
          const int r = row0 + wm * 64 + mf * 16 + kq * 4 + i;
          C[(size_t)r * N + c] = acc[mf][nf][i] + bsv;
        }
      }
    }
}

// ---- weight conversion for GRU: w_hh (3H,H) f32 -> packed f16 pairs -----
// layout: wf16[dir][th=kc*256+u][gate*64 + j], k = kc*128 + 2*j
__global__ __launch_bounds__(256) void wcvt_kernel(
    const float* __restrict__ whh_f, const float* __restrict__ whh_b,
    unsigned* __restrict__ wf16)
{
  const int gid = blockIdx.x * 256 + threadIdx.x;
  if (gid >= 2 * 512 * 192) return;
  const int dir = gid / (512 * 192);
  const int rem = gid % (512 * 192);
  const int th = rem / 192;
  const int q  = rem % 192;
  const int kc = th >> 8, u = th & 255;
  const int g = q / 64, j = q % 64;
  const int k = kc * 128 + 2 * j;
  const float* w = dir ? whh_b : whh_f;
  const float w0 = w[((size_t)g * HH + u) * HH + k];
  const float w1v = w[((size_t)g * HH + u) * HH + k + 1];
  _Float16 a = (_Float16)w0, b = (_Float16)w1v;
  u16 ua, ub;
  __builtin_memcpy(&ua, &a, 2);
  __builtin_memcpy(&ub, &b, 2);
  wf16[gid] = (unsigned)ua | ((unsigned)ub << 16);
}

// ---- single-CU GRU v6: LOOP-CARRIED weight pin --------------------------
// R9 counter closure: VGPR=120 means ~122 of 192 weight u32/thread are
// re-fetched from L2 EVERY step (~250KB/block-step); aggregate = ~50 TB/s
// demand > 34.5 TB/s L2 ceiling -> the GRU is L2-BW-bound on weight
// reloads. R5-R8 pins failed because they sat OUTSIDE the t-loop: a
// pin-once value is still reloadable inside the loop (and R8's opaque
// loads were simply spilled to scratch = same L2 traffic, VGPR 116).
// v6: assert "+v" on all 192 weight components INSIDE the loop body --
// the asm may modify them each iteration, so a reload from global would
// be incorrect; the compiler must carry them in VGPRs (232 live < 256
// cap at 2 waves/SIMD) or visibly spill. Everything else = R9 verbatim.
__global__ __launch_bounds__(512, 2) void gru_solo_kernel(
    const float* __restrict__ xg_f, const float* __restrict__ xg_b,
    const unsigned* __restrict__ wf16,
    const float* __restrict__ bhh_f, const float* __restrict__ bhh_b,
    const int* __restrict__ lengths,
    u16* __restrict__ Oh, u16* __restrict__ Ol, int mode)
{
  const int tid = threadIdx.x;
  const int bx = blockIdx.x;
  const int dir = (mode < 0) ? (bx >> 7) : mode;
  const int batch = (mode < 0) ? (bx & 127) : bx;
  const int u = tid >> 1, kc = tid & 1;     // kc in-wave: partner = lane^1
  const int len = lengths[batch];
  const float* xg = dir ? xg_b : xg_f;
  const float* bhh = dir ? bhh_b : bhh_f;

  __shared__ uint4 h16[2][32];              // 256 f16 per parity
  if (tid < 32) h16[0][tid] = make_uint4(0u, 0u, 0u, 0u);

  // weight load: 48 uint4 = 192 u32 (layout th = kc*256 + u)
  uint4 wR[16], wZ[16], wN[16];
  {
    const uint4* wb = (const uint4*)(wf16 + (size_t)(dir * 512 + kc * 256 + u) * 192);
#pragma unroll
    for (int i = 0; i < 16; i++) wR[i] = wb[i];
#pragma unroll
    for (int i = 0; i < 16; i++) wZ[i] = wb[16 + i];
#pragma unroll
    for (int i = 0; i < 16; i++) wN[i] = wb[32 + i];
  }
  const float br = bhh[u], bz = bhh[HH + u], bn = bhh[2 * HH + u];
  float hreg = 0.f;
  __syncthreads();

  int p = dir ? (len - 1) : 0;
  const int ps = dir ? -1 : 1;
  float xr = 0.f, xz = 0.f, xn = 0.f;
  if (kc == 0) {
    const float* x0 = xg + ((size_t)batch * TT + p) * G3;
    xr = x0[u]; xz = x0[HH + u]; xn = x0[2 * HH + u];
  }
  u16 oh_p = 0, ol_p = 0;                  // deferred output store
  size_t oi_p = 0;

  for (int t = 0; t < len; t++) {
    // LOOP-CARRIED PIN: asm may modify the weights each iteration ->
    // they cannot be re-fetched from global; must live in VGPRs (or
    // spill visibly). This is the one change vs R9.
#pragma unroll
    for (int c = 0; c < 16; c++) {
      asm volatile("" : "+v"(wR[c].x), "+v"(wR[c].y), "+v"(wR[c].z), "+v"(wR[c].w));
      asm volatile("" : "+v"(wZ[c].x), "+v"(wZ[c].y), "+v"(wZ[c].z), "+v"(wZ[c].w));
      asm volatile("" : "+v"(wN[c].x), "+v"(wN[c].y), "+v"(wN[c].z), "+v"(wN[c].w));
    }
    // (1) issue last step's output store (full step of slack to next drain)
    if (kc == 0 && t > 0) { Oh[oi_p] = oh_p; Ol[oi_p] = ol_p; }
    // (2) issue next step's xg prefetch (consumed next iteration)
    float nr = 0.f, nz = 0.f, nn = 0.f;
    if (kc == 0 && t + 1 < len) {
      const float* xq = xg + ((size_t)batch * TT + p + ps) * G3;
      nr = xq[u]; nz = xq[HH + u]; nn = xq[2 * HH + u];
    }
    // (3) matvec over my k-slice (uniform-addr 2-way broadcast reads)
    float aR = 0.f, aZ = 0.f, aN = 0.f;
    const uint4* hb = &h16[t & 1][kc << 4];
#pragma unroll
    for (int c = 0; c < 16; c++) {
      const uint4 hv = hb[c];
      DOT2(aR, wR[c].x, hv.x); DOT2(aZ, wZ[c].x, hv.x); DOT2(aN, wN[c].x, hv.x);
      DOT2(aR, wR[c].y, hv.y); DOT2(aZ, wZ[c].y, hv.y); DOT2(aN, wN[c].y, hv.y);
      DOT2(aR, wR[c].z, hv.z); DOT2(aZ, wZ[c].z, hv.z); DOT2(aN, wN[c].z, hv.z);
      DOT2(aR, wR[c].w, hv.w); DOT2(aZ, wZ[c].w, hv.w); DOT2(aN, wN[c].w, hv.w);
    }
    // (4) cross-kc partial sums: adjacent lanes, same wave
    aR += __shfl_xor(aR, 1);
    aZ += __shfl_xor(aZ, 1);
    aN += __shfl_xor(aN, 1);
    // (5) activation + h update (kc==0 lanes)
    if (kc == 0) {
      const float er = __expf(-(xr + aR + br));
      const float r = __builtin_amdgcn_rcpf(1.f + er);
      const float ez = __expf(-(xz + aZ + bz));
      const float z = __builtin_amdgcn_rcpf(1.f + ez);
      const float xa = xn + r * (aN + bn);
      const float e2 = __expf(-2.f * xa);
      const float th = (1.f - e2) * __builtin_amdgcn_rcpf(1.f + e2);
      const float hn = (1.f - z) * th + z * hreg;
      hreg = hn;
      ((_Float16*)h16[(t + 1) & 1])[u] = (_Float16)hn;
      split_bf16(hn, oh_p, ol_p);
      oi_p = ((size_t)batch * TT + p) * (2 * HH) + dir * HH + u;
    }
    __syncthreads();               // single barrier: h16[(t+1)&1] published
    p += ps; xr = nr; xz = nz; xn = nn;
  }
  if (kc == 0 && len > 0) { Oh[oi_p] = oh_p; Ol[oi_p] = ol_p; }
}

// ------------- scores from hmid: relu, dot w2, +b2; mask t>=len ----------
__global__ __launch_bounds__(256) void score2_kernel(
    const float* __restrict__ hmid, const float* __restrict__ w2,
    const float* __restrict__ b2, const int* __restrict__ lengths,
    float* __restrict__ scores)
{
  const int wv = threadIdx.x >> 6, lane = threadIdx.x & 63;
  const int bt = blockIdx.x * 4 + wv;
  const int b = bt >> 8, t = bt & 255;
  float v = 0.f;
  if (t < lengths[b]) {
    float hv = fmaxf(hmid[(size_t)bt * 64 + lane], 0.f);
    v = hv * w2[lane];
#pragma unroll
    for (int o = 32; o > 0; o >>= 1) v += __shfl_down(v, o);
    v += b2[0];
  }
  if (lane == 0) scores[bt] = v;
}

// -------- softmax + top-3 + normalize + seq_feat, 1 block per batch ------
// outp lives as bf16 hi/lo planes; f32 value = hi + lo (exact to 1e-5)
__global__ __launch_bounds__(256) void attn_kernel(
    const float* __restrict__ scores,
    const u16* __restrict__ Oh, const u16* __restrict__ Ol,
    const float* __restrict__ temp_ptr, const int* __restrict__ lengths,
    float* __restrict__ seq_feat)
{
  const int b = blockIdx.x;
  const int t = threadIdx.x;
  const int len = lengths[b];
  float temp = fminf(fmaxf(temp_ptr[0], 0.001f), 10.0f);
  __shared__ float red[256];
  __shared__ int redi[256];
  __shared__ float topv[3]; __shared__ int topi[3];
  __shared__ float vn[3]; __shared__ float vsum_s;
  const bool valid = t < len;
  float logit = valid ? scores[b * TT + t] / temp : -INFINITY;
  red[t] = logit; __syncthreads();
  for (int s = 128; s > 0; s >>= 1) {
    if (t < s) red[t] = fmaxf(red[t], red[t + s]);
    __syncthreads();
  }
  float mx = red[0]; __syncthreads();
  float e = valid ? expf(logit - mx) : 0.f;
  red[t] = e; __syncthreads();
  for (int s = 128; s > 0; s >>= 1) {
    if (t < s) red[t] += red[t + s];
    __syncthreads();
  }
  float sum = red[0]; __syncthreads();
  float myp = e / sum;
  for (int it = 0; it < 3; it++) {
    red[t] = myp; redi[t] = t; __syncthreads();
    for (int s = 128; s > 0; s >>= 1) {
      if (t < s) {
        float v2 = red[t + s]; int i2 = redi[t + s];
        if (v2 > red[t] || (v2 == red[t] && i2 < redi[t])) { red[t] = v2; redi[t] = i2; }
      }
      __syncthreads();
    }
    if (t == 0) { topv[it] = red[0]; topi[it] = redi[0]; }
    __syncthreads();
    if (t == topi[it]) myp = -1.f;
    __syncthreads();
  }
  if (t == 0) {
    int k_act = len < 3 ? len : 3;
    float vsum = 0.f;
    for (int jj = 0; jj < 3; jj++) if (jj < k_act) vsum += topv[jj];
    vsum_s = vsum;
    float denom = fmaxf(vsum, 1e-8f);
    for (int jj = 0; jj < 3; jj++) vn[jj] = (jj < k_act) ? topv[jj] / denom : 0.f;
  }
  __syncthreads();
  if (vsum_s > 1e-8f) {
    for (int hh = t; hh < 2 * HH; hh += 256) {
      float s = 0.f;
      for (int jj = 0; jj < 3; jj++) {
        const size_t oi = ((size_t)b * TT + topi[jj]) * (2 * HH) + hh;
        s += vn[jj] * bf_hl(Oh[oi], Ol[oi]);
      }
      seq_feat[b * 2 * HH + hh] = s;
    }
  } else {
    float inv = 1.f / ((float)len + 1e-8f);
    for (int hh = t; hh < 2 * HH; hh += 256) {
      float s = 0.f;
      for (int tt2 = 0; tt2 < len; tt2++) {
        const size_t oi = ((size_t)b * TT + tt2) * (2 * HH) + hh;
        s += bf_hl(Oh[oi], Ol[oi]);
      }
      seq_feat[b * 2 * HH + hh] = s * inv;
    }
  }
}

// ------------------- final heads: (B,11) then (B,10) ---------------------
__global__ __launch_bounds__(256) void head_kernel(
    const float* __restrict__ seq_feat,
    const float* __restrict__ w_tens, const float* __restrict__ b_tens,
    const float* __restrict__ w_ones, const float* __restrict__ b_ones,
    float* __restrict__ d_out)
{
  const int b = blockIdx.x;
  const int lane = threadIdx.x & 63, wv = threadIdx.x >> 6;
  const float* sf = seq_feat + (size_t)b * 2 * HH;
  for (int o = wv; o < 21; o += 4) {
    const float* wr = (o < 11) ? (w_tens + (size_t)o * 2 * HH)
                               : (w_ones + (size_t)(o - 11) * 2 * HH);
    float s = 0.f;
    for (int e2 = lane; e2 < 2 * HH; e2 += 64) s += sf[e2] * wr[e2];
#pragma unroll
    for (int off2 = 32; off2 > 0; off2 >>= 1) s += __shfl_down(s, off2);
    if (lane == 0) {
      if (o < 11) d_out[b * 11 + o] = s + b_tens[o];
      else d_out[BB * 11 + b * 10 + (o - 11)] = s + b_ones[o - 11];
    }
  }
}

extern "C" void kernel_launch(void* const* d_in, const int* in_sizes, int n_in,
                              void* d_out, int out_size, void* d_ws, size_t ws_size,
                              hipStream_t stream)
{
  const float* feats       = (const float*)d_in[0];
  const int*   lengths     = (const int*)d_in[1];
  const float* temperature = (const float*)d_in[2];
  const float* w_ih_f = (const float*)d_in[3];
  const float* w_hh_f = (const float*)d_in[4];
  const float* b_ih_f = (const float*)d_in[5];
  const float* b_hh_f = (const float*)d_in[6];
  const float* w_ih_b = (const float*)d_in[7];
  const float* w_hh_b = (const float*)d_in[8];
  const float* b_ih_b = (const float*)d_in[9];
  const float* b_hh_b = (const float*)d_in[10];
  const float* w1 = (const float*)d_in[11];
  const float* b1 = (const float*)d_in[12];
  const float* w2 = (const float*)d_in[13];
  const float* b2 = (const float*)d_in[14];
  const float* w_tens = (const float*)d_in[15];
  const float* b_tens = (const float*)d_in[16];
  const float* w_ones = (const float*)d_in[17];
  const float* b_ones = (const float*)d_in[18];
  float* out = (float*)d_out;

  const int    M       = BB * TT;                       // 32768
  const size_t xg_sz   = (size_t)M * G3 * 4;            // 100.7 MB
  const size_t opl_sz  = (size_t)M * 2 * HH * 2;        // 33.55 MB (one O plane)
  const size_t wgru_sz = (size_t)2 * 512 * 192 * 4;     // 786 KB
  const size_t aplane  = (size_t)M * DD * 2;            // 33.55 MB (bf16 A plane)
  const size_t wihpl   = (size_t)G3 * DD * 2;           // 786 KB
  const size_t w1pl    = (size_t)64 * 2 * HH * 2;       // 64 KB
  char* ws = (char*)d_ws;

  const size_t fused_need = 2 * xg_sz + 2 * opl_sz + wgru_sz + 4 * wihpl + 2 * w1pl;

  if (ws_size >= fused_need) {
    // -------- fused: A-split aliases the O-plane region (dead before GRU
    //          writes it); hmid/scores/seq_feat alias xg_f (dead after GRU).
    float* xg_f = (float*)ws;
    float* xg_b = (float*)(ws + xg_sz);
    u16*   Oh   = (u16*)(ws + 2 * xg_sz);
    u16*   Ol   = (u16*)(ws + 2 * xg_sz + opl_sz);
    char*  wreg = ws + 2 * xg_sz + 2 * opl_sz;
    unsigned* wgru = (unsigned*)wreg;
    u16* Wfh = (u16*)(wreg + wgru_sz);
    u16* Wfl = (u16*)(wreg + wgru_sz + wihpl);
    u16* Wbh = (u16*)(wreg + wgru_sz + 2 * wihpl);
    u16* Wbl = (u16*)(wreg + wgru_sz + 3 * wihpl);
    u16* W1h = (u16*)(wreg + wgru_sz + 4 * wihpl);
    u16* W1l = (u16*)(wreg + wgru_sz + 4 * wihpl + w1pl);
    u16* Ah  = (u16*)Oh;                        // alias (pre-GRU only)
    u16* Al  = (u16*)((char*)Oh + aplane);
    float* hmid     = xg_f;                     // alias (post-GRU only)
    float* scores   = hmid + (size_t)M * 64;
    float* seq_feat = scores + M;

    wcvt_kernel<<<768, 256, 0, stream>>>(w_hh_f, w_hh_b, wgru);
    cvt_split_kernel<<<M * DD / 8 / 256, 256, 0, stream>>>(feats, Ah, Al, M * DD / 8);
    cvt_split_kernel<<<G3 * DD / 8 / 256, 256, 0, stream>>>(w_ih_f, Wfh, Wfl, G3 * DD / 8);
    cvt_split_kernel<<<G3 * DD / 8 / 256, 256, 0, stream>>>(w_ih_b, Wbh, Wbl, G3 * DD / 8);
    cvt_split_kernel<<<16, 256, 0, stream>>>(w1, W1h, W1l, 64 * 2 * HH / 8);
    gemm_bf3<<<dim3(6, 256), 256, 0, stream>>>(Ah, Al, Wfh, Wfl, b_ih_f, xg_f, M, G3, DD);
    gemm_bf3<<<dim3(6, 256), 256, 0, stream>>>(Ah, Al, Wbh, Wbl, b_ih_b, xg_b, M, G3, DD);
    gru_solo_kernel<<<256, 512, 0, stream>>>(
        xg_f, xg_b, wgru, b_hh_f, b_hh_b, lengths, Oh, Ol, -1);
    gemm_bf3<<<dim3(1, 256), 256, 0, stream>>>(Oh, Ol, W1h, W1l, b1, hmid, M, 64, 2 * HH);
    score2_kernel<<<M / 4, 256, 0, stream>>>(hmid, w2, b2, lengths, scores);
    attn_kernel<<<BB, 256, 0, stream>>>(scores, Oh, Ol, temperature, lengths, seq_feat);
    head_kernel<<<BB, 256, 0, stream>>>(seq_feat, w_tens, b_tens, w_ones, b_ones, out);
  } else {
    // -------- fallback: single xg buffer; A-split in its own region -----
    float* xg   = (float*)ws;
    u16*   Oh   = (u16*)(ws + xg_sz);
    u16*   Ol   = (u16*)(ws + xg_sz + opl_sz);
    char*  wreg = ws + xg_sz + 2 * opl_sz;
    unsigned* wgru = (unsigned*)wreg;
    u16* Wfh = (u16*)(wreg + wgru_sz);
    u16* Wfl = (u16*)(wreg + wgru_sz + wihpl);
    u16* Wbh = (u16*)(wreg + wgru_sz + 2 * wihpl);
    u16* Wbl = (u16*)(wreg + wgru_sz + 3 * wihpl);
    u16* W1h = (u16*)(wreg + wgru_sz + 4 * wihpl);
    u16* W1l = (u16*)(wreg + wgru_sz + 4 * wihpl + w1pl);
    u16* Ah  = (u16*)(wreg + wgru_sz + 4 * wihpl + 2 * w1pl);
    u16* Al  = (u16*)((char*)Ah + aplane);
    float* hmid     = xg;                       // alias (post-GRU only)
    float* scores   = hmid + (size_t)M * 64;
    float* seq_feat = scores + M;

    wcvt_kernel<<<768, 256, 0, stream>>>(w_hh_f, w_hh_b, wgru);
    cvt_split_kernel<<<M * DD / 8 / 256, 256, 0, stream>>>(feats, Ah, Al, M * DD / 8);
    cvt_split_kernel<<<G3 * DD / 8 / 256, 256, 0, stream>>>(w_ih_f, Wfh, Wfl, G3 * DD / 8);
    cvt_split_kernel<<<G3 * DD / 8 / 256, 256, 0, stream>>>(w_ih_b, Wbh, Wbl, G3 * DD / 8);
    cvt_split_kernel<<<16, 256, 0, stream>>>(w1, W1h, W1l, 64 * 2 * HH / 8);
    gemm_bf3<<<dim3(6, 256), 256, 0, stream>>>(Ah, Al, Wfh, Wfl, b_ih_f, xg, M, G3, DD);
    gru_solo_kernel<<<BB, 512, 0, stream>>>(
        xg, xg, wgru, b_hh_f, b_hh_b, lengths, Oh, Ol, 0);
    gemm_bf3<<<dim3(6, 256), 256, 0, stream>>>(Ah, Al, Wbh, Wbl, b_ih_b, xg, M, G3, DD);
    gru_solo_kernel<<<BB, 512, 0, stream>>>(
        xg, xg, wgru, b_hh_f, b_hh_b, lengths, Oh, Ol, 1);
    gemm_bf3<<<dim3(1, 256), 256, 0, stream>>>(Oh, Ol, W1h, W1l, b1, hmid, M, 64, 2 * HH);
    score2_kernel<<<M / 4, 256, 0, stream>>>(hmid, w2, b2, lengths, scores);
    attn_kernel<<<BB, 256, 0, stream>>>(scores, Oh, Ol, temperature, lengths, seq_feat);
    head_kernel<<<BB, 256, 0, stream>>>(seq_feat, w_tens, b_tens, w_ones, b_ones, out);
  }
}

// Round 11
// 932.997 us; speedup vs baseline: 1.1285x; 1.1285x over previous
//
#include <hip/hip_runtime.h>
#include <cmath>

#define BB 128
#define TT 256
#define DD 512
#define HH 256
#define G3 768   // 3*H

typedef float f32x4 __attribute__((ext_vector_type(4)));
typedef short s16x8 __attribute__((ext_vector_type(8)));
typedef unsigned long long ull;
typedef unsigned short u16;

// v_dot2_f32_f16: acc += w.f16[0]*h.f16[0] + w.f16[1]*h.f16[1]  (CDNA1+)
#define DOT2(acc, w, h) \
  asm("v_dot2_f32_f16 %0, %1, %2, %0" : "+v"(acc) : "v"(w), "v"(h))

// RNE float -> (hi bf16, lo bf16) split: x ~= hi + lo, |err| ~ 2^-17 |x|
__device__ __forceinline__ void split_bf16(float x, u16& h, u16& l)
{
  unsigned u = __float_as_uint(x);
  unsigned hr = u + 0x7fffu + ((u >> 16) & 1u);
  h = (u16)(hr >> 16);
  float hf = __uint_as_float((unsigned)h << 16);
  float lo = x - hf;
  unsigned u2 = __float_as_uint(lo);
  unsigned lr2 = u2 + 0x7fffu + ((u2 >> 16) & 1u);
  l = (u16)(lr2 >> 16);
}

__device__ __forceinline__ float bf_hl(u16 h, u16 l)
{
  return __uint_as_float((unsigned)h << 16) + __uint_as_float((unsigned)l << 16);
}

__device__ __forceinline__ u16 f32_to_f16(float x)
{
  _Float16 h = (_Float16)x;
  u16 r; __builtin_memcpy(&r, &h, 2); return r;
}

__device__ __forceinline__ float f16_to_f32(u16 v)
{
  _Float16 h; __builtin_memcpy(&h, &v, 2); return (float)h;
}

// ---- f32 -> (hi,lo) bf16 plane conversion, 8 elems/thread ---------------
__global__ __launch_bounds__(256) void cvt_split_kernel(
    const float* __restrict__ src, u16* __restrict__ dh,
    u16* __restrict__ dl, int n8)
{
  const int i = blockIdx.x * 256 + threadIdx.x;
  if (i >= n8) return;
  const float4 v0 = *(const float4*)(src + (size_t)i * 8);
  const float4 v1 = *(const float4*)(src + (size_t)i * 8 + 4);
  float f[8] = {v0.x, v0.y, v0.z, v0.w, v1.x, v1.y, v1.z, v1.w};
  u16 hh[8], ll[8];
#pragma unroll
  for (int j = 0; j < 8; j++) split_bf16(f[j], hh[j], ll[j]);
  *(uint4*)(dh + (size_t)i * 8) = *(const uint4*)hh;
  *(uint4*)(dl + (size_t)i * 8) = *(const uint4*)ll;
}

// ---- pure-MFMA split-bf16 GEMM: 3 MFMAs per fragment (hh+hl+lh) ---------
// Compute core unchanged from R6-R10 (pass-verified). New: split-epilogue
// mode writes cols [0,512) as f16 (r,z pre-activations; sigmoid-arg
// precision ~1e-4 suffices) and cols [512,768) as f32 (n gate, needs full
// precision through tanh) -- halves the xg footprint so BOTH directions'
// xg fit the workspace and the single fused GRU launch is guaranteed.
__global__ __launch_bounds__(256) void gemm_bf3(
    const u16* __restrict__ Ah, const u16* __restrict__ Al,
    const u16* __restrict__ Wh, const u16* __restrict__ Wl,
    const float* __restrict__ bias, float* __restrict__ C,
    int M, int N, int K,
    u16* __restrict__ Crz, float* __restrict__ Cn, int split)
{
  __shared__ unsigned aH[128][20], aL[128][20], bH[128][20], bL[128][20];
  const int tid = threadIdx.x;
  const int row0 = blockIdx.y * 128, col0 = blockIdx.x * 128;
  const int wid = tid >> 6, lane = tid & 63;
  const int wm = wid >> 1, wn = wid & 1;
  const int lr = lane & 15, kq = lane >> 4;
  const int sr = tid >> 1, sh = tid & 1;     // staging: row sr, k-half sh

  f32x4 acc[4][4];
#pragma unroll
  for (int i = 0; i < 4; i++)
#pragma unroll
    for (int j = 0; j < 4; j++) acc[i][j] = (f32x4){0.f, 0.f, 0.f, 0.f};

  const u16* pah = Ah + (size_t)(row0 + sr) * K + sh * 16;
  const u16* pal = Al + (size_t)(row0 + sr) * K + sh * 16;
  const u16* pwh = Wh + (size_t)(col0 + sr) * K + sh * 16;
  const u16* pwl = Wl + (size_t)(col0 + sr) * K + sh * 16;
  const bool wok = (col0 + sr) < N;
  const uint4 z4 = make_uint4(0u, 0u, 0u, 0u);

  uint4 rah0 = *(const uint4*)(pah), rah1 = *(const uint4*)(pah + 8);
  uint4 ral0 = *(const uint4*)(pal), ral1 = *(const uint4*)(pal + 8);
  uint4 rbh0 = wok ? *(const uint4*)(pwh) : z4;
  uint4 rbh1 = wok ? *(const uint4*)(pwh + 8) : z4;
  uint4 rbl0 = wok ? *(const uint4*)(pwl) : z4;
  uint4 rbl1 = wok ? *(const uint4*)(pwl + 8) : z4;

  for (int k0 = 0; k0 < K; k0 += 32) {
    __syncthreads();               // previous compute done reading LDS
    ((uint4*)&aH[sr][sh * 8])[0] = rah0; ((uint4*)&aH[sr][sh * 8])[1] = rah1;
    ((uint4*)&aL[sr][sh * 8])[0] = ral0; ((uint4*)&aL[sr][sh * 8])[1] = ral1;
    ((uint4*)&bH[sr][sh * 8])[0] = rbh0; ((uint4*)&bH[sr][sh * 8])[1] = rbh1;
    ((uint4*)&bL[sr][sh * 8])[0] = rbl0; ((uint4*)&bL[sr][sh * 8])[1] = rbl1;
    __syncthreads();
    if (k0 + 32 < K) {             // register-prefetch next chunk
      rah0 = *(const uint4*)(pah + k0 + 32); rah1 = *(const uint4*)(pah + k0 + 40);
      ral0 = *(const uint4*)(pal + k0 + 32); ral1 = *(const uint4*)(pal + k0 + 40);
      rbh0 = wok ? *(const uint4*)(pwh + k0 + 32) : z4;
      rbh1 = wok ? *(const uint4*)(pwh + k0 + 40) : z4;
      rbl0 = wok ? *(const uint4*)(pwl + k0 + 32) : z4;
      rbl1 = wok ? *(const uint4*)(pwl + k0 + 40) : z4;
    }
    s16x8 ah[4], al4[4], bh4[4], bl4[4];
#pragma unroll
    for (int f = 0; f < 4; f++) {
      const int ra = wm * 64 + f * 16 + lr;
      const int rb = wn * 64 + f * 16 + lr;
      ah[f]  = *(const s16x8*)((const short*)&aH[ra][0] + kq * 8);
      al4[f] = *(const s16x8*)((const short*)&aL[ra][0] + kq * 8);
      bh4[f] = *(const s16x8*)((const short*)&bH[rb][0] + kq * 8);
      bl4[f] = *(const s16x8*)((const short*)&bL[rb][0] + kq * 8);
    }
#pragma unroll
    for (int mf = 0; mf < 4; mf++)
#pragma unroll
      for (int nf = 0; nf < 4; nf++) {
        acc[mf][nf] = __builtin_amdgcn_mfma_f32_16x16x32_bf16(ah[mf],  bh4[nf], acc[mf][nf], 0, 0, 0);
        acc[mf][nf] = __builtin_amdgcn_mfma_f32_16x16x32_bf16(ah[mf],  bl4[nf], acc[mf][nf], 0, 0, 0);
        acc[mf][nf] = __builtin_amdgcn_mfma_f32_16x16x32_bf16(al4[mf], bh4[nf], acc[mf][nf], 0, 0, 0);
      }
  }
  // epilogue: C/D layout col=lane&15, row=(lane>>4)*4+reg
#pragma unroll
  for (int mf = 0; mf < 4; mf++)
#pragma unroll
    for (int nf = 0; nf < 4; nf++) {
      const int c = col0 + wn * 64 + nf * 16 + lr;
      if (c < N) {
        const float bsv = bias[c];
#pragma unroll
        for (int i = 0; i < 4; i++) {
          const int r = row0 + wm * 64 + mf * 16 + kq * 4 + i;
          const float v = acc[mf][nf][i] + bsv;
          if (split) {
            if (c < 512) Crz[(size_t)r * 512 + c] = f32_to_f16(v);
            else         Cn[(size_t)r * 256 + (c - 512)] = v;
          } else {
            C[(size_t)r * N + c] = v;
          }
        }
      }
    }
}

// ---- weight conversion for GRU: w_hh (3H,H) f32 -> packed f16 pairs -----
// layout: wf16[dir][th][g*32+j]; th = 4*u + kc; k = kc*64 + 2*j
__global__ __launch_bounds__(256) void wcvt_kernel(
    const float* __restrict__ whh_f, const float* __restrict__ whh_b,
    unsigned* __restrict__ wf16)
{
  const int gid = blockIdx.x * 256 + threadIdx.x;
  if (gid >= 2 * 1024 * 96) return;
  const int dir = gid / (1024 * 96);
  const int rem = gid % (1024 * 96);
  const int th = rem / 96;
  const int q  = rem % 96;
  const int u = th >> 2, kc = th & 3;
  const int g = q / 32, j = q % 32;
  const int k = kc * 64 + 2 * j;
  const float* w = dir ? whh_b : whh_f;
  const float w0 = w[((size_t)g * HH + u) * HH + k];
  const float w1v = w[((size_t)g * HH + u) * HH + k + 1];
  _Float16 a = (_Float16)w0, b = (_Float16)w1v;
  u16 ua, ub;
  __builtin_memcpy(&ua, &a, 2);
  __builtin_memcpy(&ub, &b, 2);
  wf16[gid] = (unsigned)ua | ((unsigned)ub << 16);
}

// ---- single-CU GRU v7: 1024 threads, 96 weight-u32/thread ---------------
// R6-R10 closed the case: the allocator tops out at ~116-128 VGPRs for
// this shape no matter what (reload-from-L2 and scratch-spill cost the
// same L2 round trips; neither shows in HBM counters). Five pin idioms,
// five nulls. v7 stops fighting and SHRINKS THE ASK to fit the tier:
// 1024 threads, thread (u = tid>>2, kc = tid&3) owns gates r,z,n of unit
// u over k-slice [kc*64, kc*64+64) = 96 u32 of f16 weight pairs. With
// __launch_bounds__(1024,4) the VGPR cap is exactly 128; 96 weights +
// ~30 live state ~= 126 fits -> zero (or tiny) per-step reload. Even the
// failure mode (keeps ~86) cuts reload traffic 6x vs R10. Cross-kc
// partials: 2 shfl_xor (lanes 1,2 - same wave). One barrier/step;
// deferred output stores; 4 waves/SIMD for latency hiding.
__global__ __launch_bounds__(1024, 4) void gru_solo_kernel(
    const u16* __restrict__ xgRZ_f, const float* __restrict__ xgN_f,
    const u16* __restrict__ xgRZ_b, const float* __restrict__ xgN_b,
    const unsigned* __restrict__ wf16,
    const float* __restrict__ bhh_f, const float* __restrict__ bhh_b,
    const int* __restrict__ lengths,
    u16* __restrict__ Oh, u16* __restrict__ Ol, int mode)
{
  const int tid = threadIdx.x;
  const int bx = blockIdx.x;
  const int dir = (mode < 0) ? (bx >> 7) : mode;
  const int batch = (mode < 0) ? (bx & 127) : bx;
  const int u = tid >> 2, kc = tid & 3;
  const int len = lengths[batch];
  const u16*   xgRZ = dir ? xgRZ_b : xgRZ_f;
  const float* xgN  = dir ? xgN_b  : xgN_f;
  const float* bhh  = dir ? bhh_b  : bhh_f;

  __shared__ uint4 h16[2][32];              // 256 f16 per parity
  if (tid < 32) h16[0][tid] = make_uint4(0u, 0u, 0u, 0u);

  // weight load: 24 uint4 = 96 u32 (fits the 128-VGPR tier)
  uint4 wR[8], wZ[8], wN[8];
  {
    const uint4* wb = (const uint4*)(wf16 + (size_t)(dir * 1024 + tid) * 96);
#pragma unroll
    for (int i = 0; i < 8; i++) wR[i] = wb[i];
#pragma unroll
    for (int i = 0; i < 8; i++) wZ[i] = wb[8 + i];
#pragma unroll
    for (int i = 0; i < 8; i++) wN[i] = wb[16 + i];
  }
  const float br = bhh[u], bz = bhh[HH + u], bn = bhh[2 * HH + u];
  float hreg = 0.f;
  __syncthreads();

  int p = dir ? (len - 1) : 0;
  const int ps = dir ? -1 : 1;
  float xr = 0.f, xz = 0.f, xn = 0.f;
  if (kc == 0) {
    const size_t rz = ((size_t)batch * TT + p) * 512;
    xr = f16_to_f32(xgRZ[rz + u]);
    xz = f16_to_f32(xgRZ[rz + 256 + u]);
    xn = xgN[((size_t)batch * TT + p) * 256 + u];
  }
  u16 oh_p = 0, ol_p = 0;                  // deferred output store
  size_t oi_p = 0;

  for (int t = 0; t < len; t++) {
    // (1) issue last step's output store (full step of slack to next drain)
    if (kc == 0 && t > 0) { Oh[oi_p] = oh_p; Ol[oi_p] = ol_p; }
    // (2) issue next step's xg prefetch (consumed next iteration)
    float nr = 0.f, nz = 0.f, nn = 0.f;
    if (kc == 0 && t + 1 < len) {
      const size_t rz = ((size_t)batch * TT + p + ps) * 512;
      nr = f16_to_f32(xgRZ[rz + u]);
      nz = f16_to_f32(xgRZ[rz + 256 + u]);
      nn = xgN[((size_t)batch * TT + p + ps) * 256 + u];
    }
    // (3) matvec over my 64-elem k-slice (uniform-addr broadcast reads)
    float aR = 0.f, aZ = 0.f, aN = 0.f;
    const uint4* hb = &h16[t & 1][kc << 3];
#pragma unroll
    for (int c = 0; c < 8; c++) {
      const uint4 hv = hb[c];
      DOT2(aR, wR[c].x, hv.x); DOT2(aZ, wZ[c].x, hv.x); DOT2(aN, wN[c].x, hv.x);
      DOT2(aR, wR[c].y, hv.y); DOT2(aZ, wZ[c].y, hv.y); DOT2(aN, wN[c].y, hv.y);
      DOT2(aR, wR[c].z, hv.z); DOT2(aZ, wZ[c].z, hv.z); DOT2(aN, wN[c].z, hv.z);
      DOT2(aR, wR[c].w, hv.w); DOT2(aZ, wZ[c].w, hv.w); DOT2(aN, wN[c].w, hv.w);
    }
    // (4) cross-kc partial sums: lanes {4u..4u+3}, same wave
    aR += __shfl_xor(aR, 1); aZ += __shfl_xor(aZ, 1); aN += __shfl_xor(aN, 1);
    aR += __shfl_xor(aR, 2); aZ += __shfl_xor(aZ, 2); aN += __shfl_xor(aN, 2);
    // (5) activation + h update (kc==0 lanes = every 4th lane)
    if (kc == 0) {
      const float er = __expf(-(xr + aR + br));
      const float r = __builtin_amdgcn_rcpf(1.f + er);
      const float ez = __expf(-(xz + aZ + bz));
      const float z = __builtin_amdgcn_rcpf(1.f + ez);
      const float xa = xn + r * (aN + bn);
      const float e2 = __expf(-2.f * xa);
      const float th = (1.f - e2) * __builtin_amdgcn_rcpf(1.f + e2);
      const float hn = (1.f - z) * th + z * hreg;
      hreg = hn;
      ((_Float16*)h16[(t + 1) & 1])[u] = (_Float16)hn;
      split_bf16(hn, oh_p, ol_p);
      oi_p = ((size_t)batch * TT + p) * (2 * HH) + dir * HH + u;
    }
    __syncthreads();               // single barrier: h16[(t+1)&1] published
    p += ps; xr = nr; xz = nz; xn = nn;
  }
  if (kc == 0 && len > 0) { Oh[oi_p] = oh_p; Ol[oi_p] = ol_p; }
}

// ------------- scores from hmid: relu, dot w2, +b2; mask t>=len ----------
__global__ __launch_bounds__(256) void score2_kernel(
    const float* __restrict__ hmid, const float* __restrict__ w2,
    const float* __restrict__ b2, const int* __restrict__ lengths,
    float* __restrict__ scores)
{
  const int wv = threadIdx.x >> 6, lane = threadIdx.x & 63;
  const int bt = blockIdx.x * 4 + wv;
  const int b = bt >> 8, t = bt & 255;
  float v = 0.f;
  if (t < lengths[b]) {
    float hv = fmaxf(hmid[(size_t)bt * 64 + lane], 0.f);
    v = hv * w2[lane];
#pragma unroll
    for (int o = 32; o > 0; o >>= 1) v += __shfl_down(v, o);
    v += b2[0];
  }
  if (lane == 0) scores[bt] = v;
}

// -------- softmax + top-3 + normalize + seq_feat, 1 block per batch ------
// outp lives as bf16 hi/lo planes; f32 value = hi + lo (exact to 1e-5)
__global__ __launch_bounds__(256) void attn_kernel(
    const float* __restrict__ scores,
    const u16* __restrict__ Oh, const u16* __restrict__ Ol,
    const float* __restrict__ temp_ptr, const int* __restrict__ lengths,
    float* __restrict__ seq_feat)
{
  const int b = blockIdx.x;
  const int t = threadIdx.x;
  const int len = lengths[b];
  float temp = fminf(fmaxf(temp_ptr[0], 0.001f), 10.0f);
  __shared__ float red[256];
  __shared__ int redi[256];
  __shared__ float topv[3]; __shared__ int topi[3];
  __shared__ float vn[3]; __shared__ float vsum_s;
  const bool valid = t < len;
  float logit = valid ? scores[b * TT + t] / temp : -INFINITY;
  red[t] = logit; __syncthreads();
  for (int s = 128; s > 0; s >>= 1) {
    if (t < s) red[t] = fmaxf(red[t], red[t + s]);
    __syncthreads();
  }
  float mx = red[0]; __syncthreads();
  float e = valid ? expf(logit - mx) : 0.f;
  red[t] = e; __syncthreads();
  for (int s = 128; s > 0; s >>= 1) {
    if (t < s) red[t] += red[t + s];
    __syncthreads();
  }
  float sum = red[0]; __syncthreads();
  float myp = e / sum;
  for (int it = 0; it < 3; it++) {
    red[t] = myp; redi[t] = t; __syncthreads();
    for (int s = 128; s > 0; s >>= 1) {
      if (t < s) {
        float v2 = red[t + s]; int i2 = redi[t + s];
        if (v2 > red[t] || (v2 == red[t] && i2 < redi[t])) { red[t] = v2; redi[t] = i2; }
      }
      __syncthreads();
    }
    if (t == 0) { topv[it] = red[0]; topi[it] = redi[0]; }
    __syncthreads();
    if (t == topi[it]) myp = -1.f;
    __syncthreads();
  }
  if (t == 0) {
    int k_act = len < 3 ? len : 3;
    float vsum = 0.f;
    for (int jj = 0; jj < 3; jj++) if (jj < k_act) vsum += topv[jj];
    vsum_s = vsum;
    float denom = fmaxf(vsum, 1e-8f);
    for (int jj = 0; jj < 3; jj++) vn[jj] = (jj < k_act) ? topv[jj] / denom : 0.f;
  }
  __syncthreads();
  if (vsum_s > 1e-8f) {
    for (int hh = t; hh < 2 * HH; hh += 256) {
      float s = 0.f;
      for (int jj = 0; jj < 3; jj++) {
        const size_t oi = ((size_t)b * TT + topi[jj]) * (2 * HH) + hh;
        s += vn[jj] * bf_hl(Oh[oi], Ol[oi]);
      }
      seq_feat[b * 2 * HH + hh] = s;
    }
  } else {
    float inv = 1.f / ((float)len + 1e-8f);
    for (int hh = t; hh < 2 * HH; hh += 256) {
      float s = 0.f;
      for (int tt2 = 0; tt2 < len; tt2++) {
        const size_t oi = ((size_t)b * TT + tt2) * (2 * HH) + hh;
        s += bf_hl(Oh[oi], Ol[oi]);
      }
      seq_feat[b * 2 * HH + hh] = s * inv;
    }
  }
}

// ------------------- final heads: (B,11) then (B,10) ---------------------
__global__ __launch_bounds__(256) void head_kernel(
    const float* __restrict__ seq_feat,
    const float* __restrict__ w_tens, const float* __restrict__ b_tens,
    const float* __restrict__ w_ones, const float* __restrict__ b_ones,
    float* __restrict__ d_out)
{
  const int b = blockIdx.x;
  const int lane = threadIdx.x & 63, wv = threadIdx.x >> 6;
  const float* sf = seq_feat + (size_t)b * 2 * HH;
  for (int o = wv; o < 21; o += 4) {
    const float* wr = (o < 11) ? (w_tens + (size_t)o * 2 * HH)
                               : (w_ones + (size_t)(o - 11) * 2 * HH);
    float s = 0.f;
    for (int e2 = lane; e2 < 2 * HH; e2 += 64) s += sf[e2] * wr[e2];
#pragma unroll
    for (int off2 = 32; off2 > 0; off2 >>= 1) s += __shfl_down(s, off2);
    if (lane == 0) {
      if (o < 11) d_out[b * 11 + o] = s + b_tens[o];
      else d_out[BB * 11 + b * 10 + (o - 11)] = s + b_ones[o - 11];
    }
  }
}

extern "C" void kernel_launch(void* const* d_in, const int* in_sizes, int n_in,
                              void* d_out, int out_size, void* d_ws, size_t ws_size,
                              hipStream_t stream)
{
  const float* feats       = (const float*)d_in[0];
  const int*   lengths     = (const int*)d_in[1];
  const float* temperature = (const float*)d_in[2];
  const float* w_ih_f = (const float*)d_in[3];
  const float* w_hh_f = (const float*)d_in[4];
  const float* b_ih_f = (const float*)d_in[5];
  const float* b_hh_f = (const float*)d_in[6];
  const float* w_ih_b = (const float*)d_in[7];
  const float* w_hh_b = (const float*)d_in[8];
  const float* b_ih_b = (const float*)d_in[9];
  const float* b_hh_b = (const float*)d_in[10];
  const float* w1 = (const float*)d_in[11];
  const float* b1 = (const float*)d_in[12];
  const float* w2 = (const float*)d_in[13];
  const float* b2 = (const float*)d_in[14];
  const float* w_tens = (const float*)d_in[15];
  const float* b_tens = (const float*)d_in[16];
  const float* w_ones = (const float*)d_in[17];
  const float* b_ones = (const float*)d_in[18];
  float* out = (float*)d_out;

  const int    M       = BB * TT;                       // 32768
  const size_t xgrz_sz = (size_t)M * 512 * 2;           // 33.55 MB (f16 r,z)
  const size_t xgn_sz  = (size_t)M * 256 * 4;           // 33.55 MB (f32 n)
  const size_t opl_sz  = (size_t)M * 2 * HH * 2;        // 33.55 MB per O plane
  const size_t wgru_sz = (size_t)2 * 1024 * 96 * 4;     // 786 KB
  const size_t aplane  = (size_t)M * DD * 2;            // 33.55 MB bf16 A plane
  const size_t wihpl   = (size_t)G3 * DD * 2;           // 786 KB
  const size_t w1pl    = (size_t)64 * 2 * HH * 2;       // 64 KB
  char* ws = (char*)d_ws;

  // total need ~= 205.4 MB. R6-R10's ~272 MB "fused_need" likely exceeded
  // ws_size, silently running the fallback (TWO gru dispatches - the
  // unaccounted ~480us). The fallback ran and passed there, which proves
  // ws >= ~239 MB > 205 MB: this single fused plan always fits.
  u16*   xgRZ_f = (u16*)ws;
  float* xgN_f  = (float*)(ws + xgrz_sz);
  u16*   xgRZ_b = (u16*)(ws + xgrz_sz + xgn_sz);
  float* xgN_b  = (float*)(ws + 2 * xgrz_sz + xgn_sz);
  u16*   Oh     = (u16*)(ws + 2 * xgrz_sz + 2 * xgn_sz);
  u16*   Ol     = (u16*)(ws + 2 * xgrz_sz + 2 * xgn_sz + opl_sz);
  char*  wreg   = ws + 2 * xgrz_sz + 2 * xgn_sz + 2 * opl_sz;
  unsigned* wgru = (unsigned*)wreg;
  u16* Wfh = (u16*)(wreg + wgru_sz);
  u16* Wfl = (u16*)(wreg + wgru_sz + wihpl);
  u16* Wbh = (u16*)(wreg + wgru_sz + 2 * wihpl);
  u16* Wbl = (u16*)(wreg + wgru_sz + 3 * wihpl);
  u16* W1h = (u16*)(wreg + wgru_sz + 4 * wihpl);
  u16* W1l = (u16*)(wreg + wgru_sz + 4 * wihpl + w1pl);
  u16* Ah  = Oh;                              // alias (pre-GRU only)
  u16* Al  = Ol;                              // alias (pre-GRU only)
  float* hmid     = (float*)ws;               // alias xg region (post-GRU)
  float* scores   = hmid + (size_t)M * 64;
  float* seq_feat = scores + M;

  wcvt_kernel<<<768, 256, 0, stream>>>(w_hh_f, w_hh_b, wgru);
  cvt_split_kernel<<<M * DD / 8 / 256, 256, 0, stream>>>(feats, Ah, Al, M * DD / 8);
  cvt_split_kernel<<<G3 * DD / 8 / 256, 256, 0, stream>>>(w_ih_f, Wfh, Wfl, G3 * DD / 8);
  cvt_split_kernel<<<G3 * DD / 8 / 256, 256, 0, stream>>>(w_ih_b, Wbh, Wbl, G3 * DD / 8);
  cvt_split_kernel<<<16, 256, 0, stream>>>(w1, W1h, W1l, 64 * 2 * HH / 8);
  gemm_bf3<<<dim3(6, 256), 256, 0, stream>>>(
      Ah, Al, Wfh, Wfl, b_ih_f, nullptr, M, G3, DD, xgRZ_f, xgN_f, 1);
  gemm_bf3<<<dim3(6, 256), 256, 0, stream>>>(
      Ah, Al, Wbh, Wbl, b_ih_b, nullptr, M, G3, DD, xgRZ_b, xgN_b, 1);
  gru_solo_kernel<<<256, 1024, 0, stream>>>(
      xgRZ_f, xgN_f, xgRZ_b, xgN_b, wgru, b_hh_f, b_hh_b, lengths, Oh, Ol, -1);
  gemm_bf3<<<dim3(1, 256), 256, 0, stream>>>(
      Oh, Ol, W1h, W1l, b1, hmid, M, 64, 2 * HH, nullptr, nullptr, 0);
  score2_kernel<<<M / 4, 256, 0, stream>>>(hmid, w2, b2, lengths, scores);
  attn_kernel<<<BB, 256, 0, stream>>>(scores, Oh, Ol, temperature, lengths, seq_feat);
  head_kernel<<<BB, 256, 0, stream>>>(seq_feat, w_tens, b_tens, w_ones, b_ones, out);
}

// Round 12
// 903.333 us; speedup vs baseline: 1.1656x; 1.0328x over previous
//
#include <hip/hip_runtime.h>
#include <cmath>

#define BB 128
#define TT 256
#define DD 512
#define HH 256
#define G3 768   // 3*H

typedef float f32x4 __attribute__((ext_vector_type(4)));
typedef short s16x8 __attribute__((ext_vector_type(8)));
typedef unsigned long long ull;
typedef unsigned short u16;

// v_dot2_f32_f16: acc += w.f16[0]*h.f16[0] + w.f16[1]*h.f16[1]  (CDNA1+)
#define DOT2(acc, w, h) \
  asm("v_dot2_f32_f16 %0, %1, %2, %0" : "+v"(acc) : "v"(w), "v"(h))

// RNE float -> (hi bf16, lo bf16) split: x ~= hi + lo, |err| ~ 2^-17 |x|
__device__ __forceinline__ void split_bf16(float x, u16& h, u16& l)
{
  unsigned u = __float_as_uint(x);
  unsigned hr = u + 0x7fffu + ((u >> 16) & 1u);
  h = (u16)(hr >> 16);
  float hf = __uint_as_float((unsigned)h << 16);
  float lo = x - hf;
  unsigned u2 = __float_as_uint(lo);
  unsigned lr2 = u2 + 0x7fffu + ((u2 >> 16) & 1u);
  l = (u16)(lr2 >> 16);
}

__device__ __forceinline__ float bf_hl(u16 h, u16 l)
{
  return __uint_as_float((unsigned)h << 16) + __uint_as_float((unsigned)l << 16);
}

__device__ __forceinline__ u16 f32_to_f16(float x)
{
  _Float16 h = (_Float16)x;
  u16 r; __builtin_memcpy(&r, &h, 2); return r;
}

__device__ __forceinline__ float f16_to_f32(u16 v)
{
  _Float16 h; __builtin_memcpy(&h, &v, 2); return (float)h;
}

// ---- f32 -> (hi,lo) bf16 plane conversion, 8 elems/thread ---------------
__global__ __launch_bounds__(256) void cvt_split_kernel(
    const float* __restrict__ src, u16* __restrict__ dh,
    u16* __restrict__ dl, int n8)
{
  const int i = blockIdx.x * 256 + threadIdx.x;
  if (i >= n8) return;
  const float4 v0 = *(const float4*)(src + (size_t)i * 8);
  const float4 v1 = *(const float4*)(src + (size_t)i * 8 + 4);
  float f[8] = {v0.x, v0.y, v0.z, v0.w, v1.x, v1.y, v1.z, v1.w};
  u16 hh[8], ll[8];
#pragma unroll
  for (int j = 0; j < 8; j++) split_bf16(f[j], hh[j], ll[j]);
  *(uint4*)(dh + (size_t)i * 8) = *(const uint4*)hh;
  *(uint4*)(dl + (size_t)i * 8) = *(const uint4*)ll;
}

// ---- pure-MFMA split-bf16 GEMM, ROW-PANEL form --------------------------
// Grid (1, M/128): each block owns a 128-row panel and loops over column
// tiles internally -> A panel is fetched from HBM/L3 ONCE (R6-R11 had a
// grid column dim, re-reading A 6x -- R5's row-panel fix, restored).
// Compute core unchanged (pass-verified). Split-epilogue mode writes cols
// [0,512) as f16 (r,z pre-activations) and [512,768) as f32 (n gate).
__global__ __launch_bounds__(256) void gemm_bf3(
    const u16* __restrict__ Ah, const u16* __restrict__ Al,
    const u16* __restrict__ Wh, const u16* __restrict__ Wl,
    const float* __restrict__ bias, float* __restrict__ C,
    int M, int N, int K,
    u16* __restrict__ Crz, float* __restrict__ Cn, int split)
{
  __shared__ unsigned aH[128][20], aL[128][20], bH[128][20], bL[128][20];
  const int tid = threadIdx.x;
  const int row0 = blockIdx.y * 128;
  const int wid = tid >> 6, lane = tid & 63;
  const int wm = wid >> 1, wn = wid & 1;
  const int lr = lane & 15, kq = lane >> 4;
  const int sr = tid >> 1, sh = tid & 1;     // staging: row sr, k-half sh
  const int NT = (N + 127) >> 7;

  const u16* pah = Ah + (size_t)(row0 + sr) * K + sh * 16;
  const u16* pal = Al + (size_t)(row0 + sr) * K + sh * 16;
  const uint4 z4 = make_uint4(0u, 0u, 0u, 0u);

  for (int ct = 0; ct < NT; ct++) {
    const int col0 = ct * 128;
    f32x4 acc[4][4];
#pragma unroll
    for (int i = 0; i < 4; i++)
#pragma unroll
      for (int j = 0; j < 4; j++) acc[i][j] = (f32x4){0.f, 0.f, 0.f, 0.f};

    const u16* pwh = Wh + (size_t)(col0 + sr) * K + sh * 16;
    const u16* pwl = Wl + (size_t)(col0 + sr) * K + sh * 16;
    const bool wok = (col0 + sr) < N;

    uint4 rah0 = *(const uint4*)(pah), rah1 = *(const uint4*)(pah + 8);
    uint4 ral0 = *(const uint4*)(pal), ral1 = *(const uint4*)(pal + 8);
    uint4 rbh0 = wok ? *(const uint4*)(pwh) : z4;
    uint4 rbh1 = wok ? *(const uint4*)(pwh + 8) : z4;
    uint4 rbl0 = wok ? *(const uint4*)(pwl) : z4;
    uint4 rbl1 = wok ? *(const uint4*)(pwl + 8) : z4;

    for (int k0 = 0; k0 < K; k0 += 32) {
      __syncthreads();               // previous compute done reading LDS
      ((uint4*)&aH[sr][sh * 8])[0] = rah0; ((uint4*)&aH[sr][sh * 8])[1] = rah1;
      ((uint4*)&aL[sr][sh * 8])[0] = ral0; ((uint4*)&aL[sr][sh * 8])[1] = ral1;
      ((uint4*)&bH[sr][sh * 8])[0] = rbh0; ((uint4*)&bH[sr][sh * 8])[1] = rbh1;
      ((uint4*)&bL[sr][sh * 8])[0] = rbl0; ((uint4*)&bL[sr][sh * 8])[1] = rbl1;
      __syncthreads();
      if (k0 + 32 < K) {             // register-prefetch next chunk
        rah0 = *(const uint4*)(pah + k0 + 32); rah1 = *(const uint4*)(pah + k0 + 40);
        ral0 = *(const uint4*)(pal + k0 + 32); ral1 = *(const uint4*)(pal + k0 + 40);
        rbh0 = wok ? *(const uint4*)(pwh + k0 + 32) : z4;
        rbh1 = wok ? *(const uint4*)(pwh + k0 + 40) : z4;
        rbl0 = wok ? *(const uint4*)(pwl + k0 + 32) : z4;
        rbl1 = wok ? *(const uint4*)(pwl + k0 + 40) : z4;
      }
      s16x8 ah[4], al4[4], bh4[4], bl4[4];
#pragma unroll
      for (int f = 0; f < 4; f++) {
        const int ra = wm * 64 + f * 16 + lr;
        const int rb = wn * 64 + f * 16 + lr;
        ah[f]  = *(const s16x8*)((const short*)&aH[ra][0] + kq * 8);
        al4[f] = *(const s16x8*)((const short*)&aL[ra][0] + kq * 8);
        bh4[f] = *(const s16x8*)((const short*)&bH[rb][0] + kq * 8);
        bl4[f] = *(const s16x8*)((const short*)&bL[rb][0] + kq * 8);
      }
#pragma unroll
      for (int mf = 0; mf < 4; mf++)
#pragma unroll
        for (int nf = 0; nf < 4; nf++) {
          acc[mf][nf] = __builtin_amdgcn_mfma_f32_16x16x32_bf16(ah[mf],  bh4[nf], acc[mf][nf], 0, 0, 0);
          acc[mf][nf] = __builtin_amdgcn_mfma_f32_16x16x32_bf16(ah[mf],  bl4[nf], acc[mf][nf], 0, 0, 0);
          acc[mf][nf] = __builtin_amdgcn_mfma_f32_16x16x32_bf16(al4[mf], bh4[nf], acc[mf][nf], 0, 0, 0);
        }
    }
    // epilogue: C/D layout col=lane&15, row=(lane>>4)*4+reg
#pragma unroll
    for (int mf = 0; mf < 4; mf++)
#pragma unroll
      for (int nf = 0; nf < 4; nf++) {
        const int c = col0 + wn * 64 + nf * 16 + lr;
        if (c < N) {
          const float bsv = bias[c];
#pragma unroll
          for (int i = 0; i < 4; i++) {
            const int r = row0 + wm * 64 + mf * 16 + kq * 4 + i;
            const float v = acc[mf][nf][i] + bsv;
            if (split) {
              if (c < 512) Crz[(size_t)r * 512 + c] = f32_to_f16(v);
              else         Cn[(size_t)r * 256 + (c - 512)] = v;
            } else {
              C[(size_t)r * N + c] = v;
            }
          }
        }
      }
    __syncthreads();               // LDS safe for next ct's staging
  }
}

// ---- weight conversion for GRU: w_hh (3H,H) f32 -> packed f16 pairs -----
// layout: wf16[dir][th=kc*256+u][gate*64 + j], k = kc*128 + 2*j
__global__ __launch_bounds__(256) void wcvt_kernel(
    const float* __restrict__ whh_f, const float* __restrict__ whh_b,
    unsigned* __restrict__ wf16)
{
  const int gid = blockIdx.x * 256 + threadIdx.x;
  if (gid >= 2 * 512 * 192) return;
  const int dir = gid / (512 * 192);
  const int rem = gid % (512 * 192);
  const int th = rem / 192;
  const int q  = rem % 192;
  const int kc = th >> 8, u = th & 255;
  const int g = q / 64, j = q % 64;
  const int k = kc * 128 + 2 * j;
  const float* w = dir ? whh_b : whh_f;
  const float w0 = w[((size_t)g * HH + u) * HH + k];
  const float w1v = w[((size_t)g * HH + u) * HH + k + 1];
  _Float16 a = (_Float16)w0, b = (_Float16)w1v;
  u16 ua, ub;
  __builtin_memcpy(&ua, &a, 2);
  __builtin_memcpy(&ub, &b, 2);
  wf16[gid] = (unsigned)ua | ((unsigned)ub << 16);
}

// ---- single-CU GRU v8: waves_per_eu(2,2) pins the occupancy tier --------
// R6-R11 established: __launch_bounds__ only CEILS VGPR use; the allocator
// freely picks a HIGHER-occupancy/lower-VGPR tier (R11: chose 64 VGPRs at
// a 128 cap) and eats ~400KB/step of L2 weight reloads instead. The
// documented lever that pins occupancy from ABOVE is
// __attribute__((amdgpu_waves_per_eu(min,max))): with (2,2) the RA's
// occupancy target is fixed at 2 waves/EU -- no reward remains for
// shrinking below the 256-VGPR budget, so the 192 weight u32 + ~35 state
// can actually be kept resident (256 is also the architectural VALU VGPR
// cap, so 192/thread is the largest satisfiable ask).
// Structure = R9/R10 (pass-verified): 512 thr, u=tid>>1, kc=tid&1 (in-wave
// partials, one shfl_xor), ONE barrier/step, deferred output stores,
// split-xg inputs (f16 r,z + f32 n).
__global__ __launch_bounds__(512)
__attribute__((amdgpu_waves_per_eu(2, 2)))
void gru_solo_kernel(
    const u16* __restrict__ xgRZ_f, const float* __restrict__ xgN_f,
    const u16* __restrict__ xgRZ_b, const float* __restrict__ xgN_b,
    const unsigned* __restrict__ wf16,
    const float* __restrict__ bhh_f, const float* __restrict__ bhh_b,
    const int* __restrict__ lengths,
    u16* __restrict__ Oh, u16* __restrict__ Ol, int mode)
{
  const int tid = threadIdx.x;
  const int bx = blockIdx.x;
  const int dir = (mode < 0) ? (bx >> 7) : mode;
  const int batch = (mode < 0) ? (bx & 127) : bx;
  const int u = tid >> 1, kc = tid & 1;     // kc in-wave: partner = lane^1
  const int len = lengths[batch];
  const u16*   xgRZ = dir ? xgRZ_b : xgRZ_f;
  const float* xgN  = dir ? xgN_b  : xgN_f;
  const float* bhh  = dir ? bhh_b  : bhh_f;

  __shared__ uint4 h16[2][32];              // 256 f16 per parity
  if (tid < 32) h16[0][tid] = make_uint4(0u, 0u, 0u, 0u);

  // weight load: 48 uint4 = 192 u32 (layout th = kc*256 + u)
  uint4 wR[16], wZ[16], wN[16];
  {
    const uint4* wb = (const uint4*)(wf16 + (size_t)(dir * 512 + kc * 256 + u) * 192);
#pragma unroll
    for (int i = 0; i < 16; i++) wR[i] = wb[i];
#pragma unroll
    for (int i = 0; i < 16; i++) wZ[i] = wb[16 + i];
#pragma unroll
    for (int i = 0; i < 16; i++) wN[i] = wb[32 + i];
  }
  const float br = bhh[u], bz = bhh[HH + u], bn = bhh[2 * HH + u];
  float hreg = 0.f;
  __syncthreads();

  int p = dir ? (len - 1) : 0;
  const int ps = dir ? -1 : 1;
  float xr = 0.f, xz = 0.f, xn = 0.f;
  if (kc == 0) {
    const size_t rz = ((size_t)batch * TT + p) * 512;
    xr = f16_to_f32(xgRZ[rz + u]);
    xz = f16_to_f32(xgRZ[rz + 256 + u]);
    xn = xgN[((size_t)batch * TT + p) * 256 + u];
  }
  u16 oh_p = 0, ol_p = 0;                  // deferred output store
  size_t oi_p = 0;

  for (int t = 0; t < len; t++) {
    // (1) issue last step's output store (full step of slack to next drain)
    if (kc == 0 && t > 0) { Oh[oi_p] = oh_p; Ol[oi_p] = ol_p; }
    // (2) issue next step's xg prefetch (consumed next iteration)
    float nr = 0.f, nz = 0.f, nn = 0.f;
    if (kc == 0 && t + 1 < len) {
      const size_t rz = ((size_t)batch * TT + p + ps) * 512;
      nr = f16_to_f32(xgRZ[rz + u]);
      nz = f16_to_f32(xgRZ[rz + 256 + u]);
      nn = xgN[((size_t)batch * TT + p + ps) * 256 + u];
    }
    // (3) matvec over my 128-elem k-slice (uniform-addr broadcast reads)
    float aR = 0.f, aZ = 0.f, aN = 0.f;
    const uint4* hb = &h16[t & 1][kc << 4];
#pragma unroll
    for (int c = 0; c < 16; c++) {
      const uint4 hv = hb[c];
      DOT2(aR, wR[c].x, hv.x); DOT2(aZ, wZ[c].x, hv.x); DOT2(aN, wN[c].x, hv.x);
      DOT2(aR, wR[c].y, hv.y); DOT2(aZ, wZ[c].y, hv.y); DOT2(aN, wN[c].y, hv.y);
      DOT2(aR, wR[c].z, hv.z); DOT2(aZ, wZ[c].z, hv.z); DOT2(aN, wN[c].z, hv.z);
      DOT2(aR, wR[c].w, hv.w); DOT2(aZ, wZ[c].w, hv.w); DOT2(aN, wN[c].w, hv.w);
    }
    // (4) cross-kc partial sums: adjacent lanes, same wave
    aR += __shfl_xor(aR, 1);
    aZ += __shfl_xor(aZ, 1);
    aN += __shfl_xor(aN, 1);
    // (5) activation + h update (kc==0 lanes)
    if (kc == 0) {
      const float er = __expf(-(xr + aR + br));
      const float r = __builtin_amdgcn_rcpf(1.f + er);
      const float ez = __expf(-(xz + aZ + bz));
      const float z = __builtin_amdgcn_rcpf(1.f + ez);
      const float xa = xn + r * (aN + bn);
      const float e2 = __expf(-2.f * xa);
      const float th = (1.f - e2) * __builtin_amdgcn_rcpf(1.f + e2);
      const float hn = (1.f - z) * th + z * hreg;
      hreg = hn;
      ((_Float16*)h16[(t + 1) & 1])[u] = (_Float16)hn;
      split_bf16(hn, oh_p, ol_p);
      oi_p = ((size_t)batch * TT + p) * (2 * HH) + dir * HH + u;
    }
    __syncthreads();               // single barrier: h16[(t+1)&1] published
    p += ps; xr = nr; xz = nz; xn = nn;
  }
  if (kc == 0 && len > 0) { Oh[oi_p] = oh_p; Ol[oi_p] = ol_p; }
}

// ------------- scores from hmid: relu, dot w2, +b2; mask t>=len ----------
__global__ __launch_bounds__(256) void score2_kernel(
    const float* __restrict__ hmid, const float* __restrict__ w2,
    const float* __restrict__ b2, const int* __restrict__ lengths,
    float* __restrict__ scores)
{
  const int wv = threadIdx.x >> 6, lane = threadIdx.x & 63;
  const int bt = blockIdx.x * 4 + wv;
  const int b = bt >> 8, t = bt & 255;
  float v = 0.f;
  if (t < lengths[b]) {
    float hv = fmaxf(hmid[(size_t)bt * 64 + lane], 0.f);
    v = hv * w2[lane];
#pragma unroll
    for (int o = 32; o > 0; o >>= 1) v += __shfl_down(v, o);
    v += b2[0];
  }
  if (lane == 0) scores[bt] = v;
}

// -------- softmax + top-3 + normalize + seq_feat, 1 block per batch ------
// outp lives as bf16 hi/lo planes; f32 value = hi + lo (exact to 1e-5)
__global__ __launch_bounds__(256) void attn_kernel(
    const float* __restrict__ scores,
    const u16* __restrict__ Oh, const u16* __restrict__ Ol,
    const float* __restrict__ temp_ptr, const int* __restrict__ lengths,
    float* __restrict__ seq_feat)
{
  const int b = blockIdx.x;
  const int t = threadIdx.x;
  const int len = lengths[b];
  float temp = fminf(fmaxf(temp_ptr[0], 0.001f), 10.0f);
  __shared__ float red[256];
  __shared__ int redi[256];
  __shared__ float topv[3]; __shared__ int topi[3];
  __shared__ float vn[3]; __shared__ float vsum_s;
  const bool valid = t < len;
  float logit = valid ? scores[b * TT + t] / temp : -INFINITY;
  red[t] = logit; __syncthreads();
  for (int s = 128; s > 0; s >>= 1) {
    if (t < s) red[t] = fmaxf(red[t], red[t + s]);
    __syncthreads();
  }
  float mx = red[0]; __syncthreads();
  float e = valid ? expf(logit - mx) : 0.f;
  red[t] = e; __syncthreads();
  for (int s = 128; s > 0; s >>= 1) {
    if (t < s) red[t] += red[t + s];
    __syncthreads();
  }
  float sum = red[0]; __syncthreads();
  float myp = e / sum;
  for (int it = 0; it < 3; it++) {
    red[t] = myp; redi[t] = t; __syncthreads();
    for (int s = 128; s > 0; s >>= 1) {
      if (t < s) {
        float v2 = red[t + s]; int i2 = redi[t + s];
        if (v2 > red[t] || (v2 == red[t] && i2 < redi[t])) { red[t] = v2; redi[t] = i2; }
      }
      __syncthreads();
    }
    if (t == 0) { topv[it] = red[0]; topi[it] = redi[0]; }
    __syncthreads();
    if (t == topi[it]) myp = -1.f;
    __syncthreads();
  }
  if (t == 0) {
    int k_act = len < 3 ? len : 3;
    float vsum = 0.f;
    for (int jj = 0; jj < 3; jj++) if (jj < k_act) vsum += topv[jj];
    vsum_s = vsum;
    float denom = fmaxf(vsum, 1e-8f);
    for (int jj = 0; jj < 3; jj++) vn[jj] = (jj < k_act) ? topv[jj] / denom : 0.f;
  }
  __syncthreads();
  if (vsum_s > 1e-8f) {
    for (int hh = t; hh < 2 * HH; hh += 256) {
      float s = 0.f;
      for (int jj = 0; jj < 3; jj++) {
        const size_t oi = ((size_t)b * TT + topi[jj]) * (2 * HH) + hh;
        s += vn[jj] * bf_hl(Oh[oi], Ol[oi]);
      }
      seq_feat[b * 2 * HH + hh] = s;
    }
  } else {
    float inv = 1.f / ((float)len + 1e-8f);
    for (int hh = t; hh < 2 * HH; hh += 256) {
      float s = 0.f;
      for (int tt2 = 0; tt2 < len; tt2++) {
        const size_t oi = ((size_t)b * TT + tt2) * (2 * HH) + hh;
        s += bf_hl(Oh[oi], Ol[oi]);
      }
      seq_feat[b * 2 * HH + hh] = s * inv;
    }
  }
}

// ------------------- final heads: (B,11) then (B,10) ---------------------
__global__ __launch_bounds__(256) void head_kernel(
    const float* __restrict__ seq_feat,
    const float* __restrict__ w_tens, const float* __restrict__ b_tens,
    const float* __restrict__ w_ones, const float* __restrict__ b_ones,
    float* __restrict__ d_out)
{
  const int b = blockIdx.x;
  const int lane = threadIdx.x & 63, wv = threadIdx.x >> 6;
  const float* sf = seq_feat + (size_t)b * 2 * HH;
  for (int o = wv; o < 21; o += 4) {
    const float* wr = (o < 11) ? (w_tens + (size_t)o * 2 * HH)
                               : (w_ones + (size_t)(o - 11) * 2 * HH);
    float s = 0.f;
    for (int e2 = lane; e2 < 2 * HH; e2 += 64) s += sf[e2] * wr[e2];
#pragma unroll
    for (int off2 = 32; off2 > 0; off2 >>= 1) s += __shfl_down(s, off2);
    if (lane == 0) {
      if (o < 11) d_out[b * 11 + o] = s + b_tens[o];
      else d_out[BB * 11 + b * 10 + (o - 11)] = s + b_ones[o - 11];
    }
  }
}

extern "C" void kernel_launch(void* const* d_in, const int* in_sizes, int n_in,
                              void* d_out, int out_size, void* d_ws, size_t ws_size,
                              hipStream_t stream)
{
  const float* feats       = (const float*)d_in[0];
  const int*   lengths     = (const int*)d_in[1];
  const float* temperature = (const float*)d_in[2];
  const float* w_ih_f = (const float*)d_in[3];
  const float* w_hh_f = (const float*)d_in[4];
  const float* b_ih_f = (const float*)d_in[5];
  const float* b_hh_f = (const float*)d_in[6];
  const float* w_ih_b = (const float*)d_in[7];
  const float* w_hh_b = (const float*)d_in[8];
  const float* b_ih_b = (const float*)d_in[9];
  const float* b_hh_b = (const float*)d_in[10];
  const float* w1 = (const float*)d_in[11];
  const float* b1 = (const float*)d_in[12];
  const float* w2 = (const float*)d_in[13];
  const float* b2 = (const float*)d_in[14];
  const float* w_tens = (const float*)d_in[15];
  const float* b_tens = (const float*)d_in[16];
  const float* w_ones = (const float*)d_in[17];
  const float* b_ones = (const float*)d_in[18];
  float* out = (float*)d_out;

  const int    M       = BB * TT;                       // 32768
  const size_t xgrz_sz = (size_t)M * 512 * 2;           // 33.55 MB (f16 r,z)
  const size_t xgn_sz  = (size_t)M * 256 * 4;           // 33.55 MB (f32 n)
  const size_t opl_sz  = (size_t)M * 2 * HH * 2;        // 33.55 MB per O plane
  const size_t wgru_sz = (size_t)2 * 512 * 192 * 4;     // 786 KB
  const size_t wihpl   = (size_t)G3 * DD * 2;           // 786 KB
  const size_t w1pl    = (size_t)64 * 2 * HH * 2;       // 64 KB
  char* ws = (char*)d_ws;

  // total ~= 205.4 MB -- proven to fit (R11 ran this single fused plan).
  u16*   xgRZ_f = (u16*)ws;
  float* xgN_f  = (float*)(ws + xgrz_sz);
  u16*   xgRZ_b = (u16*)(ws + xgrz_sz + xgn_sz);
  float* xgN_b  = (float*)(ws + 2 * xgrz_sz + xgn_sz);
  u16*   Oh     = (u16*)(ws + 2 * xgrz_sz + 2 * xgn_sz);
  u16*   Ol     = (u16*)(ws + 2 * xgrz_sz + 2 * xgn_sz + opl_sz);
  char*  wreg   = ws + 2 * xgrz_sz + 2 * xgn_sz + 2 * opl_sz;
  unsigned* wgru = (unsigned*)wreg;
  u16* Wfh = (u16*)(wreg + wgru_sz);
  u16* Wfl = (u16*)(wreg + wgru_sz + wihpl);
  u16* Wbh = (u16*)(wreg + wgru_sz + 2 * wihpl);
  u16* Wbl = (u16*)(wreg + wgru_sz + 3 * wihpl);
  u16* W1h = (u16*)(wreg + wgru_sz + 4 * wihpl);
  u16* W1l = (u16*)(wreg + wgru_sz + 4 * wihpl + w1pl);
  u16* Ah  = Oh;                              // alias (pre-GRU only)
  u16* Al  = Ol;                              // alias (pre-GRU only)
  float* hmid     = (float*)ws;               // alias xg region (post-GRU)
  float* scores   = hmid + (size_t)M * 64;
  float* seq_feat = scores + M;

  wcvt_kernel<<<768, 256, 0, stream>>>(w_hh_f, w_hh_b, wgru);
  cvt_split_kernel<<<M * DD / 8 / 256, 256, 0, stream>>>(feats, Ah, Al, M * DD / 8);
  cvt_split_kernel<<<G3 * DD / 8 / 256, 256, 0, stream>>>(w_ih_f, Wfh, Wfl, G3 * DD / 8);
  cvt_split_kernel<<<G3 * DD / 8 / 256, 256, 0, stream>>>(w_ih_b, Wbh, Wbl, G3 * DD / 8);
  cvt_split_kernel<<<16, 256, 0, stream>>>(w1, W1h, W1l, 64 * 2 * HH / 8);
  gemm_bf3<<<dim3(1, 256), 256, 0, stream>>>(
      Ah, Al, Wfh, Wfl, b_ih_f, nullptr, M, G3, DD, xgRZ_f, xgN_f, 1);
  gemm_bf3<<<dim3(1, 256), 256, 0, stream>>>(
      Ah, Al, Wbh, Wbl, b_ih_b, nullptr, M, G3, DD, xgRZ_b, xgN_b, 1);
  gru_solo_kernel<<<256, 512, 0, stream>>>(
      xgRZ_f, xgN_f, xgRZ_b, xgN_b, wgru, b_hh_f, b_hh_b, lengths, Oh, Ol, -1);
  gemm_bf3<<<dim3(1, 256), 256, 0, stream>>>(
      Oh, Ol, W1h, W1l, b1, hmid, M, 64, 2 * HH, nullptr, nullptr, 0);
  score2_kernel<<<M / 4, 256, 0, stream>>>(hmid, w2, b2, lengths, scores);
  attn_kernel<<<BB, 256, 0, stream>>>(scores, Oh, Ol, temperature, lengths, seq_feat);
  head_kernel<<<BB, 256, 0, stream>>>(seq_feat, w_tens, b_tens, w_ones, b_ones, out);
}

// Round 13
// 766.393 us; speedup vs baseline: 1.3738x; 1.1787x over previous
//
#include <hip/hip_runtime.h>
#include <cmath>

#define BB 128
#define TT 256
#define DD 512
#define HH 256
#define G3 768   // 3*H

typedef float f32x4 __attribute__((ext_vector_type(4)));
typedef short s16x8 __attribute__((ext_vector_type(8)));
typedef unsigned long long ull;
typedef unsigned short u16;

// v_dot2_f32_f16: acc += w.f16[0]*h.f16[0] + w.f16[1]*h.f16[1]  (CDNA1+)
#define DOT2(acc, w, h) \
  asm("v_dot2_f32_f16 %0, %1, %2, %0" : "+v"(acc) : "v"(w), "v"(h))

// RNE float -> (hi bf16, lo bf16) split: x ~= hi + lo, |err| ~ 2^-17 |x|
__device__ __forceinline__ void split_bf16(float x, u16& h, u16& l)
{
  unsigned u = __float_as_uint(x);
  unsigned hr = u + 0x7fffu + ((u >> 16) & 1u);
  h = (u16)(hr >> 16);
  float hf = __uint_as_float((unsigned)h << 16);
  float lo = x - hf;
  unsigned u2 = __float_as_uint(lo);
  unsigned lr2 = u2 + 0x7fffu + ((u2 >> 16) & 1u);
  l = (u16)(lr2 >> 16);
}

__device__ __forceinline__ float bf_hl(u16 h, u16 l)
{
  return __uint_as_float((unsigned)h << 16) + __uint_as_float((unsigned)l << 16);
}

__device__ __forceinline__ u16 f32_to_f16(float x)
{
  _Float16 h = (_Float16)x;
  u16 r; __builtin_memcpy(&r, &h, 2); return r;
}

__device__ __forceinline__ float f16_to_f32(u16 v)
{
  _Float16 h; __builtin_memcpy(&h, &v, 2); return (float)h;
}

// ---- f32 -> (hi,lo) bf16 plane conversion, 8 elems/thread ---------------
__global__ __launch_bounds__(256) void cvt_split_kernel(
    const float* __restrict__ src, u16* __restrict__ dh,
    u16* __restrict__ dl, int n8)
{
  const int i = blockIdx.x * 256 + threadIdx.x;
  if (i >= n8) return;
  const float4 v0 = *(const float4*)(src + (size_t)i * 8);
  const float4 v1 = *(const float4*)(src + (size_t)i * 8 + 4);
  float f[8] = {v0.x, v0.y, v0.z, v0.w, v1.x, v1.y, v1.z, v1.w};
  u16 hh[8], ll[8];
#pragma unroll
  for (int j = 0; j < 8; j++) split_bf16(f[j], hh[j], ll[j]);
  *(uint4*)(dh + (size_t)i * 8) = *(const uint4*)hh;
  *(uint4*)(dl + (size_t)i * 8) = *(const uint4*)ll;
}

// ---- pure-MFMA split-bf16 GEMM: 3 MFMAs per fragment (hh+hl+lh) ---------
// Grid (N/128, M/128) RESTORED (R12's row-panel form cut parallelism 6x
// to save A-reads that were L3-resident anyway -- net 157us regression).
// Split-epilogue mode writes cols [0,512) as f16 (r,z pre-activations)
// and [512,768) as f32 (n gate).
__global__ __launch_bounds__(256) void gemm_bf3(
    const u16* __restrict__ Ah, const u16* __restrict__ Al,
    const u16* __restrict__ Wh, const u16* __restrict__ Wl,
    const float* __restrict__ bias, float* __restrict__ C,
    int M, int N, int K,
    u16* __restrict__ Crz, float* __restrict__ Cn, int split)
{
  __shared__ unsigned aH[128][20], aL[128][20], bH[128][20], bL[128][20];
  const int tid = threadIdx.x;
  const int row0 = blockIdx.y * 128, col0 = blockIdx.x * 128;
  const int wid = tid >> 6, lane = tid & 63;
  const int wm = wid >> 1, wn = wid & 1;
  const int lr = lane & 15, kq = lane >> 4;
  const int sr = tid >> 1, sh = tid & 1;     // staging: row sr, k-half sh

  f32x4 acc[4][4];
#pragma unroll
  for (int i = 0; i < 4; i++)
#pragma unroll
    for (int j = 0; j < 4; j++) acc[i][j] = (f32x4){0.f, 0.f, 0.f, 0.f};

  const u16* pah = Ah + (size_t)(row0 + sr) * K + sh * 16;
  const u16* pal = Al + (size_t)(row0 + sr) * K + sh * 16;
  const u16* pwh = Wh + (size_t)(col0 + sr) * K + sh * 16;
  const u16* pwl = Wl + (size_t)(col0 + sr) * K + sh * 16;
  const bool wok = (col0 + sr) < N;
  const uint4 z4 = make_uint4(0u, 0u, 0u, 0u);

  uint4 rah0 = *(const uint4*)(pah), rah1 = *(const uint4*)(pah + 8);
  uint4 ral0 = *(const uint4*)(pal), ral1 = *(const uint4*)(pal + 8);
  uint4 rbh0 = wok ? *(const uint4*)(pwh) : z4;
  uint4 rbh1 = wok ? *(const uint4*)(pwh + 8) : z4;
  uint4 rbl0 = wok ? *(const uint4*)(pwl) : z4;
  uint4 rbl1 = wok ? *(const uint4*)(pwl + 8) : z4;

  for (int k0 = 0; k0 < K; k0 += 32) {
    __syncthreads();               // previous compute done reading LDS
    ((uint4*)&aH[sr][sh * 8])[0] = rah0; ((uint4*)&aH[sr][sh * 8])[1] = rah1;
    ((uint4*)&aL[sr][sh * 8])[0] = ral0; ((uint4*)&aL[sr][sh * 8])[1] = ral1;
    ((uint4*)&bH[sr][sh * 8])[0] = rbh0; ((uint4*)&bH[sr][sh * 8])[1] = rbh1;
    ((uint4*)&bL[sr][sh * 8])[0] = rbl0; ((uint4*)&bL[sr][sh * 8])[1] = rbl1;
    __syncthreads();
    if (k0 + 32 < K) {             // register-prefetch next chunk
      rah0 = *(const uint4*)(pah + k0 + 32); rah1 = *(const uint4*)(pah + k0 + 40);
      ral0 = *(const uint4*)(pal + k0 + 32); ral1 = *(const uint4*)(pal + k0 + 40);
      rbh0 = wok ? *(const uint4*)(pwh + k0 + 32) : z4;
      rbh1 = wok ? *(const uint4*)(pwh + k0 + 40) : z4;
      rbl0 = wok ? *(const uint4*)(pwl + k0 + 32) : z4;
      rbl1 = wok ? *(const uint4*)(pwl + k0 + 40) : z4;
    }
    s16x8 ah[4], al4[4], bh4[4], bl4[4];
#pragma unroll
    for (int f = 0; f < 4; f++) {
      const int ra = wm * 64 + f * 16 + lr;
      const int rb = wn * 64 + f * 16 + lr;
      ah[f]  = *(const s16x8*)((const short*)&aH[ra][0] + kq * 8);
      al4[f] = *(const s16x8*)((const short*)&aL[ra][0] + kq * 8);
      bh4[f] = *(const s16x8*)((const short*)&bH[rb][0] + kq * 8);
      bl4[f] = *(const s16x8*)((const short*)&bL[rb][0] + kq * 8);
    }
#pragma unroll
    for (int mf = 0; mf < 4; mf++)
#pragma unroll
      for (int nf = 0; nf < 4; nf++) {
        acc[mf][nf] = __builtin_amdgcn_mfma_f32_16x16x32_bf16(ah[mf],  bh4[nf], acc[mf][nf], 0, 0, 0);
        acc[mf][nf] = __builtin_amdgcn_mfma_f32_16x16x32_bf16(ah[mf],  bl4[nf], acc[mf][nf], 0, 0, 0);
        acc[mf][nf] = __builtin_amdgcn_mfma_f32_16x16x32_bf16(al4[mf], bh4[nf], acc[mf][nf], 0, 0, 0);
      }
  }
  // epilogue: C/D layout col=lane&15, row=(lane>>4)*4+reg
#pragma unroll
  for (int mf = 0; mf < 4; mf++)
#pragma unroll
    for (int nf = 0; nf < 4; nf++) {
      const int c = col0 + wn * 64 + nf * 16 + lr;
      if (c < N) {
        const float bsv = bias[c];
#pragma unroll
        for (int i = 0; i < 4; i++) {
          const int r = row0 + wm * 64 + mf * 16 + kq * 4 + i;
          const float v = acc[mf][nf][i] + bsv;
          if (split) {
            if (c < 512) Crz[(size_t)r * 512 + c] = f32_to_f16(v);
            else         Cn[(size_t)r * 256 + (c - 512)] = v;
          } else {
            C[(size_t)r * N + c] = v;
          }
        }
      }
    }
}

// ---- weight conversion for GRU: w_hh (3H,H) f32 -> packed f16 pairs -----
// layout: wf16[dir][th=kc*256+u][gate*64 + j], k = kc*128 + 2*j
__global__ __launch_bounds__(256) void wcvt_kernel(
    const float* __restrict__ whh_f, const float* __restrict__ whh_b,
    unsigned* __restrict__ wf16)
{
  const int gid = blockIdx.x * 256 + threadIdx.x;
  if (gid >= 2 * 512 * 192) return;
  const int dir = gid / (512 * 192);
  const int rem = gid % (512 * 192);
  const int th = rem / 192;
  const int q  = rem % 192;
  const int kc = th >> 8, u = th & 255;
  const int g = q / 64, j = q % 64;
  const int k = kc * 128 + 2 * j;
  const float* w = dir ? whh_b : whh_f;
  const float w0 = w[((size_t)g * HH + u) * HH + k];
  const float w1v = w[((size_t)g * HH + u) * HH + k + 1];
  _Float16 a = (_Float16)w0, b = (_Float16)w1v;
  u16 ua, ub;
  __builtin_memcpy(&ua, &a, 2);
  __builtin_memcpy(&ub, &b, 2);
  wf16[gid] = (unsigned)ua | ((unsigned)ub << 16);
}

// ---- single-CU GRU v9 = R10 structure + split-xg inputs -----------------
// GRU status: ACCEPTED at its aggregate-L2-BW floor (~50MB weight stream
// per step across 256 CUs ~= the 34.5 TB/s L2 ceiling). Seven residency
// experiments (R5-R12: SROA shapes, asm-opaque loads, loop-carried pins,
// waves_per_eu) all null -- the allocator holds ~96 of 192 weight u32 and
// streams the rest from L2; that is the structure's floor. R12's
// waves_per_eu(2,2) REGRESSED 345->381 by co-locating blocks (occupancy
// 6->12%, doubled per-CU L2 contention) -- dropped here. Structure:
// 512 thr, u=tid>>1, kc=tid&1 (in-wave partials via one shfl_xor), ONE
// barrier/step, deferred output stores, split-xg inputs (f16 r,z + f32 n).
__global__ __launch_bounds__(512, 1) void gru_solo_kernel(
    const u16* __restrict__ xgRZ_f, const float* __restrict__ xgN_f,
    const u16* __restrict__ xgRZ_b, const float* __restrict__ xgN_b,
    const unsigned* __restrict__ wf16,
    const float* __restrict__ bhh_f, const float* __restrict__ bhh_b,
    const int* __restrict__ lengths,
    u16* __restrict__ Oh, u16* __restrict__ Ol, int mode)
{
  const int tid = threadIdx.x;
  const int bx = blockIdx.x;
  const int dir = (mode < 0) ? (bx >> 7) : mode;
  const int batch = (mode < 0) ? (bx & 127) : bx;
  const int u = tid >> 1, kc = tid & 1;     // kc in-wave: partner = lane^1
  const int len = lengths[batch];
  const u16*   xgRZ = dir ? xgRZ_b : xgRZ_f;
  const float* xgN  = dir ? xgN_b  : xgN_f;
  const float* bhh  = dir ? bhh_b  : bhh_f;

  __shared__ uint4 h16[2][32];              // 256 f16 per parity
  if (tid < 32) h16[0][tid] = make_uint4(0u, 0u, 0u, 0u);

  // weight load: 48 uint4 = 192 u32 (layout th = kc*256 + u)
  uint4 wR[16], wZ[16], wN[16];
  {
    const uint4* wb = (const uint4*)(wf16 + (size_t)(dir * 512 + kc * 256 + u) * 192);
#pragma unroll
    for (int i = 0; i < 16; i++) wR[i] = wb[i];
#pragma unroll
    for (int i = 0; i < 16; i++) wZ[i] = wb[16 + i];
#pragma unroll
    for (int i = 0; i < 16; i++) wN[i] = wb[32 + i];
  }
  const float br = bhh[u], bz = bhh[HH + u], bn = bhh[2 * HH + u];
  float hreg = 0.f;
  __syncthreads();

  int p = dir ? (len - 1) : 0;
  const int ps = dir ? -1 : 1;
  float xr = 0.f, xz = 0.f, xn = 0.f;
  if (kc == 0) {
    const size_t rz = ((size_t)batch * TT + p) * 512;
    xr = f16_to_f32(xgRZ[rz + u]);
    xz = f16_to_f32(xgRZ[rz + 256 + u]);
    xn = xgN[((size_t)batch * TT + p) * 256 + u];
  }
  u16 oh_p = 0, ol_p = 0;                  // deferred output store
  size_t oi_p = 0;

  for (int t = 0; t < len; t++) {
    // (1) issue last step's output store (full step of slack to next drain)
    if (kc == 0 && t > 0) { Oh[oi_p] = oh_p; Ol[oi_p] = ol_p; }
    // (2) issue next step's xg prefetch (consumed next iteration)
    float nr = 0.f, nz = 0.f, nn = 0.f;
    if (kc == 0 && t + 1 < len) {
      const size_t rz = ((size_t)batch * TT + p + ps) * 512;
      nr = f16_to_f32(xgRZ[rz + u]);
      nz = f16_to_f32(xgRZ[rz + 256 + u]);
      nn = xgN[((size_t)batch * TT + p + ps) * 256 + u];
    }
    // (3) matvec over my 128-elem k-slice (uniform-addr broadcast reads)
    float aR = 0.f, aZ = 0.f, aN = 0.f;
    const uint4* hb = &h16[t & 1][kc << 4];
#pragma unroll
    for (int c = 0; c < 16; c++) {
      const uint4 hv = hb[c];
      DOT2(aR, wR[c].x, hv.x); DOT2(aZ, wZ[c].x, hv.x); DOT2(aN, wN[c].x, hv.x);
      DOT2(aR, wR[c].y, hv.y); DOT2(aZ, wZ[c].y, hv.y); DOT2(aN, wN[c].y, hv.y);
      DOT2(aR, wR[c].z, hv.z); DOT2(aZ, wZ[c].z, hv.z); DOT2(aN, wN[c].z, hv.z);
      DOT2(aR, wR[c].w, hv.w); DOT2(aZ, wZ[c].w, hv.w); DOT2(aN, wN[c].w, hv.w);
    }
    // (4) cross-kc partial sums: adjacent lanes, same wave
    aR += __shfl_xor(aR, 1);
    aZ += __shfl_xor(aZ, 1);
    aN += __shfl_xor(aN, 1);
    // (5) activation + h update (kc==0 lanes)
    if (kc == 0) {
      const float er = __expf(-(xr + aR + br));
      const float r = __builtin_amdgcn_rcpf(1.f + er);
      const float ez = __expf(-(xz + aZ + bz));
      const float z = __builtin_amdgcn_rcpf(1.f + ez);
      const float xa = xn + r * (aN + bn);
      const float e2 = __expf(-2.f * xa);
      const float th = (1.f - e2) * __builtin_amdgcn_rcpf(1.f + e2);
      const float hn = (1.f - z) * th + z * hreg;
      hreg = hn;
      ((_Float16*)h16[(t + 1) & 1])[u] = (_Float16)hn;
      split_bf16(hn, oh_p, ol_p);
      oi_p = ((size_t)batch * TT + p) * (2 * HH) + dir * HH + u;
    }
    __syncthreads();               // single barrier: h16[(t+1)&1] published
    p += ps; xr = nr; xz = nz; xn = nn;
  }
  if (kc == 0 && len > 0) { Oh[oi_p] = oh_p; Ol[oi_p] = ol_p; }
}

// ------------- scores from hmid: relu, dot w2, +b2; mask t>=len ----------
__global__ __launch_bounds__(256) void score2_kernel(
    const float* __restrict__ hmid, const float* __restrict__ w2,
    const float* __restrict__ b2, const int* __restrict__ lengths,
    float* __restrict__ scores)
{
  const int wv = threadIdx.x >> 6, lane = threadIdx.x & 63;
  const int bt = blockIdx.x * 4 + wv;
  const int b = bt >> 8, t = bt & 255;
  float v = 0.f;
  if (t < lengths[b]) {
    float hv = fmaxf(hmid[(size_t)bt * 64 + lane], 0.f);
    v = hv * w2[lane];
#pragma unroll
    for (int o = 32; o > 0; o >>= 1) v += __shfl_down(v, o);
    v += b2[0];
  }
  if (lane == 0) scores[bt] = v;
}

// -------- softmax + top-3 + normalize + seq_feat, 1 block per batch ------
// outp lives as bf16 hi/lo planes; f32 value = hi + lo (exact to 1e-5)
__global__ __launch_bounds__(256) void attn_kernel(
    const float* __restrict__ scores,
    const u16* __restrict__ Oh, const u16* __restrict__ Ol,
    const float* __restrict__ temp_ptr, const int* __restrict__ lengths,
    float* __restrict__ seq_feat)
{
  const int b = blockIdx.x;
  const int t = threadIdx.x;
  const int len = lengths[b];
  float temp = fminf(fmaxf(temp_ptr[0], 0.001f), 10.0f);
  __shared__ float red[256];
  __shared__ int redi[256];
  __shared__ float topv[3]; __shared__ int topi[3];
  __shared__ float vn[3]; __shared__ float vsum_s;
  const bool valid = t < len;
  float logit = valid ? scores[b * TT + t] / temp : -INFINITY;
  red[t] = logit; __syncthreads();
  for (int s = 128; s > 0; s >>= 1) {
    if (t < s) red[t] = fmaxf(red[t], red[t + s]);
    __syncthreads();
  }
  float mx = red[0]; __syncthreads();
  float e = valid ? expf(logit - mx) : 0.f;
  red[t] = e; __syncthreads();
  for (int s = 128; s > 0; s >>= 1) {
    if (t < s) red[t] += red[t + s];
    __syncthreads();
  }
  float sum = red[0]; __syncthreads();
  float myp = e / sum;
  for (int it = 0; it < 3; it++) {
    red[t] = myp; redi[t] = t; __syncthreads();
    for (int s = 128; s > 0; s >>= 1) {
      if (t < s) {
        float v2 = red[t + s]; int i2 = redi[t + s];
        if (v2 > red[t] || (v2 == red[t] && i2 < redi[t])) { red[t] = v2; redi[t] = i2; }
      }
      __syncthreads();
    }
    if (t == 0) { topv[it] = red[0]; topi[it] = redi[0]; }
    __syncthreads();
    if (t == topi[it]) myp = -1.f;
    __syncthreads();
  }
  if (t == 0) {
    int k_act = len < 3 ? len : 3;
    float vsum = 0.f;
    for (int jj = 0; jj < 3; jj++) if (jj < k_act) vsum += topv[jj];
    vsum_s = vsum;
    float denom = fmaxf(vsum, 1e-8f);
    for (int jj = 0; jj < 3; jj++) vn[jj] = (jj < k_act) ? topv[jj] / denom : 0.f;
  }
  __syncthreads();
  if (vsum_s > 1e-8f) {
    for (int hh = t; hh < 2 * HH; hh += 256) {
      float s = 0.f;
      for (int jj = 0; jj < 3; jj++) {
        const size_t oi = ((size_t)b * TT + topi[jj]) * (2 * HH) + hh;
        s += vn[jj] * bf_hl(Oh[oi], Ol[oi]);
      }
      seq_feat[b * 2 * HH + hh] = s;
    }
  } else {
    float inv = 1.f / ((float)len + 1e-8f);
    for (int hh = t; hh < 2 * HH; hh += 256) {
      float s = 0.f;
      for (int tt2 = 0; tt2 < len; tt2++) {
        const size_t oi = ((size_t)b * TT + tt2) * (2 * HH) + hh;
        s += bf_hl(Oh[oi], Ol[oi]);
      }
      seq_feat[b * 2 * HH + hh] = s * inv;
    }
  }
}

// ------------------- final heads: (B,11) then (B,10) ---------------------
__global__ __launch_bounds__(256) void head_kernel(
    const float* __restrict__ seq_feat,
    const float* __restrict__ w_tens, const float* __restrict__ b_tens,
    const float* __restrict__ w_ones, const float* __restrict__ b_ones,
    float* __restrict__ d_out)
{
  const int b = blockIdx.x;
  const int lane = threadIdx.x & 63, wv = threadIdx.x >> 6;
  const float* sf = seq_feat + (size_t)b * 2 * HH;
  for (int o = wv; o < 21; o += 4) {
    const float* wr = (o < 11) ? (w_tens + (size_t)o * 2 * HH)
                               : (w_ones + (size_t)(o - 11) * 2 * HH);
    float s = 0.f;
    for (int e2 = lane; e2 < 2 * HH; e2 += 64) s += sf[e2] * wr[e2];
#pragma unroll
    for (int off2 = 32; off2 > 0; off2 >>= 1) s += __shfl_down(s, off2);
    if (lane == 0) {
      if (o < 11) d_out[b * 11 + o] = s + b_tens[o];
      else d_out[BB * 11 + b * 10 + (o - 11)] = s + b_ones[o - 11];
    }
  }
}

extern "C" void kernel_launch(void* const* d_in, const int* in_sizes, int n_in,
                              void* d_out, int out_size, void* d_ws, size_t ws_size,
                              hipStream_t stream)
{
  const float* feats       = (const float*)d_in[0];
  const int*   lengths     = (const int*)d_in[1];
  const float* temperature = (const float*)d_in[2];
  const float* w_ih_f = (const float*)d_in[3];
  const float* w_hh_f = (const float*)d_in[4];
  const float* b_ih_f = (const float*)d_in[5];
  const float* b_hh_f = (const float*)d_in[6];
  const float* w_ih_b = (const float*)d_in[7];
  const float* w_hh_b = (const float*)d_in[8];
  const float* b_ih_b = (const float*)d_in[9];
  const float* b_hh_b = (const float*)d_in[10];
  const float* w1 = (const float*)d_in[11];
  const float* b1 = (const float*)d_in[12];
  const float* w2 = (const float*)d_in[13];
  const float* b2 = (const float*)d_in[14];
  const float* w_tens = (const float*)d_in[15];
  const float* b_tens = (const float*)d_in[16];
  const float* w_ones = (const float*)d_in[17];
  const float* b_ones = (const float*)d_in[18];
  float* out = (float*)d_out;

  const int    M       = BB * TT;                       // 32768
  const size_t xgrz_sz = (size_t)M * 512 * 2;           // 33.55 MB (f16 r,z)
  const size_t xgn_sz  = (size_t)M * 256 * 4;           // 33.55 MB (f32 n)
  const size_t opl_sz  = (size_t)M * 2 * HH * 2;        // 33.55 MB per O plane
  const size_t wgru_sz = (size_t)2 * 512 * 192 * 4;     // 786 KB
  const size_t wihpl   = (size_t)G3 * DD * 2;           // 786 KB
  const size_t w1pl    = (size_t)64 * 2 * HH * 2;       // 64 KB
  char* ws = (char*)d_ws;

  // total ~= 205.4 MB -- proven to fit (R11/R12 ran this single fused plan).
  u16*   xgRZ_f = (u16*)ws;
  float* xgN_f  = (float*)(ws + xgrz_sz);
  u16*   xgRZ_b = (u16*)(ws + xgrz_sz + xgn_sz);
  float* xgN_b  = (float*)(ws + 2 * xgrz_sz + xgn_sz);
  u16*   Oh     = (u16*)(ws + 2 * xgrz_sz + 2 * xgn_sz);
  u16*   Ol     = (u16*)(ws + 2 * xgrz_sz + 2 * xgn_sz + opl_sz);
  char*  wreg   = ws + 2 * xgrz_sz + 2 * xgn_sz + 2 * opl_sz;
  unsigned* wgru = (unsigned*)wreg;
  u16* Wfh = (u16*)(wreg + wgru_sz);
  u16* Wfl = (u16*)(wreg + wgru_sz + wihpl);
  u16* Wbh = (u16*)(wreg + wgru_sz + 2 * wihpl);
  u16* Wbl = (u16*)(wreg + wgru_sz + 3 * wihpl);
  u16* W1h = (u16*)(wreg + wgru_sz + 4 * wihpl);
  u16* W1l = (u16*)(wreg + wgru_sz + 4 * wihpl + w1pl);
  u16* Ah  = Oh;                              // alias (pre-GRU only)
  u16* Al  = Ol;                              // alias (pre-GRU only)
  float* hmid     = (float*)ws;               // alias xg region (post-GRU)
  float* scores   = hmid + (size_t)M * 64;
  float* seq_feat = scores + M;

  wcvt_kernel<<<768, 256, 0, stream>>>(w_hh_f, w_hh_b, wgru);
  cvt_split_kernel<<<M * DD / 8 / 256, 256, 0, stream>>>(feats, Ah, Al, M * DD / 8);
  cvt_split_kernel<<<G3 * DD / 8 / 256, 256, 0, stream>>>(w_ih_f, Wfh, Wfl, G3 * DD / 8);
  cvt_split_kernel<<<G3 * DD / 8 / 256, 256, 0, stream>>>(w_ih_b, Wbh, Wbl, G3 * DD / 8);
  cvt_split_kernel<<<16, 256, 0, stream>>>(w1, W1h, W1l, 64 * 2 * HH / 8);
  gemm_bf3<<<dim3(6, 256), 256, 0, stream>>>(
      Ah, Al, Wfh, Wfl, b_ih_f, nullptr, M, G3, DD, xgRZ_f, xgN_f, 1);
  gemm_bf3<<<dim3(6, 256), 256, 0, stream>>>(
      Ah, Al, Wbh, Wbl, b_ih_b, nullptr, M, G3, DD, xgRZ_b, xgN_b, 1);
  gru_solo_kernel<<<256, 512, 0, stream>>>(
      xgRZ_f, xgN_f, xgRZ_b, xgN_b, wgru, b_hh_f, b_hh_b, lengths, Oh, Ol, -1);
  gemm_bf3<<<dim3(1, 256), 256, 0, stream>>>(
      Oh, Ol, W1h, W1l, b1, hmid, M, 64, 2 * HH, nullptr, nullptr, 0);
  score2_kernel<<<M / 4, 256, 0, stream>>>(hmid, w2, b2, lengths, scores);
  attn_kernel<<<BB, 256, 0, stream>>>(scores, Oh, Ol, temperature, lengths, seq_feat);
  head_kernel<<<BB, 256, 0, stream>>>(seq_feat, w_tens, b_tens, w_ones, b_ones, out);
}